// Round 1
// baseline (652.680 us; speedup 1.0000x reference)
//
#include <hip/hip_runtime.h>

#define NV2 163842
#define NV1 40962
#define NV0 10242

// ---------- float <-> orderable-uint encoding for atomic max ----------
__device__ __forceinline__ unsigned fenc(float f) {
  unsigned u = __float_as_uint(f);
  return (u & 0x80000000u) ? ~u : (u | 0x80000000u);
}
__device__ __forceinline__ float fdec(unsigned k) {
  unsigned u = (k & 0x80000000u) ? (k & 0x7FFFFFFFu) : ~k;
  return __uint_as_float(u);
}

__global__ __launch_bounds__(256) void pool_init_k(unsigned* __restrict__ out, int n) {
  int i = blockIdx.x * 256 + threadIdx.x;
  if (i < n) out[i] = 0x007FFFFFu;  // fenc(-inf)
}

template <int C>
__global__ __launch_bounds__(256) void pool_scatter_k(const float* __restrict__ in,
                                                      const int* __restrict__ map,
                                                      unsigned* __restrict__ out,
                                                      int nchild) {
  int i = blockIdx.x * 256 + threadIdx.x;
  if (i < nchild * C) {
    int v = i / C, c = i % C;
    atomicMax(&out[map[v] * C + c], fenc(in[i]));
  }
}

__global__ __launch_bounds__(256) void pool_decode_k(unsigned* __restrict__ buf, int n) {
  int i = blockIdx.x * 256 + threadIdx.x;
  if (i < n) buf[i] = __float_as_uint(fdec(buf[i]));
}

// ---------- fused EdgeConv: gather-avg + linear + leaky ----------
// feature row of "virtual" input u[v] = concat(A[mapA ? mapA[v] : v], B[v])
template <int CA, int CB>
__device__ __forceinline__ float ldF(const float* __restrict__ A,
                                     const int* __restrict__ mapA,
                                     const float* __restrict__ B, int v, int c) {
  if constexpr (CB == 0) {
    return A[(size_t)v * CA + c];
  } else {
    return (c < CA) ? A[(size_t)mapA[v] * CA + c] : B[(size_t)v * CB + (c - CA)];
  }
}

template <int CA, int CB, int COUT>
__global__ __launch_bounds__(256) void edgeconv_k(
    const float* __restrict__ A, const int* __restrict__ mapA,
    const float* __restrict__ B, const int* __restrict__ src,
    const float* __restrict__ W, const float* __restrict__ bias,
    float* __restrict__ out, int nv) {
  constexpr int C = CA + CB;
  constexpr int CIN = 2 * C;
  constexpr int VB = 16;             // vertices per block
  constexpr int TG = 256 / COUT;     // vertex groups in compute phase
  constexpr int VPT = VB / TG;       // vertices per thread

  __shared__ float xl[VB][CIN];

  const int t = threadIdx.x;
  const int vbase = blockIdx.x * VB;

  // ---- phase A: gather x = [local ; avg_nb - local] into LDS ----
  for (int idx = t; idx < VB * C; idx += 256) {
    int vi = idx / C, c = idx % C;
    int v = vbase + vi;
    if (v < nv) {
      float loc = ldF<CA, CB>(A, mapA, B, v, c);
      const int* sp = src + (size_t)v * 6;
      float s = 0.f;
#pragma unroll
      for (int k = 0; k < 6; ++k) s += ldF<CA, CB>(A, mapA, B, sp[k], c);
      xl[vi][c] = loc;
      xl[vi][C + c] = s * (1.f / 6.f) - loc;
    }
  }
  __syncthreads();

  // ---- phase B: y = W x + b, leaky 0.3 ----
  const int co = t % COUT;
  const int vig = t / COUT;
  float acc[VPT];
#pragma unroll
  for (int j = 0; j < VPT; ++j) acc[j] = bias[co];
  const float* __restrict__ wr = W + (size_t)co * CIN;
#pragma unroll 4
  for (int ci = 0; ci < CIN; ++ci) {
    float w = wr[ci];
#pragma unroll
    for (int j = 0; j < VPT; ++j) acc[j] += w * xl[vig * VPT + j][ci];
  }
#pragma unroll
  for (int j = 0; j < VPT; ++j) {
    int v = vbase + vig * VPT + j;
    if (v < nv) {
      float y = acc[j];
      out[(size_t)v * COUT + co] = (y >= 0.f) ? y : 0.3f * y;
    }
  }
}

extern "C" void kernel_launch(void* const* d_in, const int* in_sizes, int n_in,
                              void* d_out, int out_size, void* d_ws, size_t ws_size,
                              hipStream_t stream) {
  const float* features = (const float*)d_in[0];
  const int* src2 = (const int*)d_in[1];
  const int* src1 = (const int*)d_in[3];
  const int* src0 = (const int*)d_in[5];
  const int* p21 = (const int*)d_in[7];
  const int* p10 = (const int*)d_in[8];
  const float* w_enc0 = (const float*)d_in[9];
  const float* b_enc0 = (const float*)d_in[10];
  const float* w_enc1 = (const float*)d_in[11];
  const float* b_enc1 = (const float*)d_in[12];
  const float* w_enc2 = (const float*)d_in[13];
  const float* b_enc2 = (const float*)d_in[14];
  const float* w_dec0 = (const float*)d_in[15];
  const float* b_dec0 = (const float*)d_in[16];
  const float* w_dec1 = (const float*)d_in[17];
  const float* b_dec1 = (const float*)d_in[18];

  float* f2  = (float*)d_ws;                    // [NV2,32]
  float* f1p = f2  + (size_t)NV2 * 32;          // [NV1,32]
  float* f1  = f1p + (size_t)NV1 * 32;          // [NV1,64]
  float* f0p = f1  + (size_t)NV1 * 64;          // [NV0,64]
  float* f0  = f0p + (size_t)NV0 * 64;          // [NV0,128]
  float* d1  = f0  + (size_t)NV0 * 128;         // [NV1,64]
  float* out = (float*)d_out;                   // [NV2,32]

  auto cdiv = [](int a, int b) { return (a + b - 1) / b; };

  // encoder level 2
  edgeconv_k<16, 0, 32><<<cdiv(NV2, 16), 256, 0, stream>>>(
      features, nullptr, nullptr, src2, w_enc0, b_enc0, f2, NV2);

  // pool 2->1 (C=32)
  pool_init_k<<<cdiv(NV1 * 32, 256), 256, 0, stream>>>((unsigned*)f1p, NV1 * 32);
  pool_scatter_k<32><<<cdiv(NV2 * 32, 256), 256, 0, stream>>>(f2, p21, (unsigned*)f1p, NV2);
  pool_decode_k<<<cdiv(NV1 * 32, 256), 256, 0, stream>>>((unsigned*)f1p, NV1 * 32);

  // encoder level 1
  edgeconv_k<32, 0, 64><<<cdiv(NV1, 16), 256, 0, stream>>>(
      f1p, nullptr, nullptr, src1, w_enc1, b_enc1, f1, NV1);

  // pool 1->0 (C=64)
  pool_init_k<<<cdiv(NV0 * 64, 256), 256, 0, stream>>>((unsigned*)f0p, NV0 * 64);
  pool_scatter_k<64><<<cdiv(NV1 * 64, 256), 256, 0, stream>>>(f1, p10, (unsigned*)f0p, NV1);
  pool_decode_k<<<cdiv(NV0 * 64, 256), 256, 0, stream>>>((unsigned*)f0p, NV0 * 64);

  // encoder level 0
  edgeconv_k<64, 0, 128><<<cdiv(NV0, 16), 256, 0, stream>>>(
      f0p, nullptr, nullptr, src0, w_enc2, b_enc2, f0, NV0);

  // decoder level 1: u1 = concat(f0[p10], f1) -> d1
  edgeconv_k<128, 64, 64><<<cdiv(NV1, 16), 256, 0, stream>>>(
      f0, p10, f1, src1, w_dec0, b_dec0, d1, NV1);

  // decoder level 2: u2 = concat(d1[p21], f2) -> out
  edgeconv_k<64, 32, 32><<<cdiv(NV2, 16), 256, 0, stream>>>(
      d1, p21, f2, src2, w_dec1, b_dec1, out, NV2);
}

// Round 2
// 563.021 us; speedup vs baseline: 1.1592x; 1.1592x over previous
//
#include <hip/hip_runtime.h>

#define NV2 163842
#define NV1 40962
#define NV0 10242

using u32 = unsigned int;
using u16 = unsigned short;

// ---------- float <-> orderable-uint encoding for atomic max ----------
__device__ __forceinline__ u32 fenc(float f) {
  u32 u = __float_as_uint(f);
  return (u & 0x80000000u) ? ~u : (u | 0x80000000u);
}
__device__ __forceinline__ float fdec(u32 k) {
  u32 u = (k & 0x80000000u) ? (k & 0x7FFFFFFFu) : ~k;
  return __uint_as_float(u);
}
// RNE float->bf16 bits
__device__ __forceinline__ u16 f2bf(float f) {
  u32 u = __float_as_uint(f);
  return (u16)((u + 0x7FFFu + ((u >> 16) & 1u)) >> 16);
}

__global__ __launch_bounds__(256) void cvt_bf_k(const float* __restrict__ in,
                                                u16* __restrict__ out, int n) {
  int i = blockIdx.x * 256 + threadIdx.x;
  if (i < n) out[i] = f2bf(in[i]);
}

// ---------- pooling: identity-prefix init + tail-only atomic max ----------
template <int C>
__global__ __launch_bounds__(256) void pool_init_k(const float* __restrict__ in,
                                                   u32* __restrict__ out, int nparent) {
  int i = blockIdx.x * 256 + threadIdx.x;
  if (i < nparent * C) out[i] = fenc(in[i]);  // map[p] == p for p < nparent
}

template <int C>
__global__ __launch_bounds__(256) void pool_tail_k(const float* __restrict__ in,
                                                   const int* __restrict__ map,
                                                   u32* __restrict__ out,
                                                   int nparent, int nchild) {
  int i = blockIdx.x * 256 + threadIdx.x;
  int tail = (nchild - nparent) * C;
  if (i < tail) {
    int v = nparent + i / C, c = i % C;
    atomicMax(&out[(size_t)map[v] * C + c], fenc(in[(size_t)v * C + c]));
  }
}

__global__ __launch_bounds__(256) void pool_decode_k(u32* __restrict__ buf,
                                                     u16* __restrict__ outbf, int n) {
  int i = blockIdx.x * 256 + threadIdx.x;
  if (i < n) {
    float f = fdec(buf[i]);
    buf[i] = __float_as_uint(f);
    outbf[i] = f2bf(f);
  }
}

// ---------- fused EdgeConv: bf16 quad gathers + fp32 local + linear + leaky ----------
template <int CA, int CB, int COUT>
__global__ __launch_bounds__(256) void edgeconv_k(
    const float* __restrict__ A32, const u16* __restrict__ Abf,
    const int* __restrict__ mapA,
    const float* __restrict__ B32, const u16* __restrict__ Bbf,
    const int* __restrict__ src,
    const float* __restrict__ W, const float* __restrict__ bias,
    float* __restrict__ out, u16* __restrict__ outbf, int nv) {
  constexpr int C = CA + CB;
  constexpr int CIN = 2 * C;
  constexpr int Q = C / 4;           // bf16 quads per virtual row
  constexpr int VB = 16;             // vertices per block
  constexpr int TG = 256 / COUT;     // vertex groups in compute phase
  constexpr int VPT = VB / TG;       // vertices per thread

  __shared__ float xl[VB][CIN];

  const int t = threadIdx.x;
  const int vbase = blockIdx.x * VB;

  // ---- phase A: x = [local ; avg_nb - local] into LDS ----
  for (int idx = t; idx < VB * Q; idx += 256) {
    int vi = idx / Q, q = idx % Q, c0 = q * 4;
    int v = vbase + vi;
    if (v < nv) {
      float4 loc;
      if constexpr (CB == 0) {
        loc = *(const float4*)&A32[(size_t)v * CA + c0];
      } else {
        if (c0 < CA) loc = *(const float4*)&A32[(size_t)mapA[v] * CA + c0];
        else         loc = *(const float4*)&B32[(size_t)v * CB + (c0 - CA)];
      }
      float s0 = 0.f, s1 = 0.f, s2 = 0.f, s3 = 0.f;
      const int* sp = src + (size_t)v * 6;
#pragma unroll
      for (int k = 0; k < 6; ++k) {
        int s = sp[k];
        uint2 u;
        if constexpr (CB == 0) {
          u = *(const uint2*)&Abf[(size_t)s * CA + c0];
        } else {
          if (c0 < CA) u = *(const uint2*)&Abf[(size_t)mapA[s] * CA + c0];
          else         u = *(const uint2*)&Bbf[(size_t)s * CB + (c0 - CA)];
        }
        s0 += __uint_as_float(u.x << 16);
        s1 += __uint_as_float(u.x & 0xFFFF0000u);
        s2 += __uint_as_float(u.y << 16);
        s3 += __uint_as_float(u.y & 0xFFFF0000u);
      }
      constexpr float inv6 = 1.f / 6.f;
      *(float4*)&xl[vi][c0] = loc;
      float4 d;
      d.x = s0 * inv6 - loc.x; d.y = s1 * inv6 - loc.y;
      d.z = s2 * inv6 - loc.z; d.w = s3 * inv6 - loc.w;
      *(float4*)&xl[vi][C + c0] = d;
    }
  }
  __syncthreads();

  // ---- phase B: y = W x + b, leaky 0.3 ----
  const int co = t % COUT;
  const int vig = t / COUT;
  float acc[VPT];
#pragma unroll
  for (int j = 0; j < VPT; ++j) acc[j] = bias[co];
  const float* __restrict__ wr = W + (size_t)co * CIN;
#pragma unroll 4
  for (int ci = 0; ci < CIN; ++ci) {
    float w = wr[ci];
#pragma unroll
    for (int j = 0; j < VPT; ++j) acc[j] += w * xl[vig * VPT + j][ci];
  }
#pragma unroll
  for (int j = 0; j < VPT; ++j) {
    int v = vbase + vig * VPT + j;
    if (v < nv) {
      float y = acc[j];
      y = (y >= 0.f) ? y : 0.3f * y;
      out[(size_t)v * COUT + co] = y;
      if (outbf != nullptr) outbf[(size_t)v * COUT + co] = f2bf(y);
    }
  }
}

extern "C" void kernel_launch(void* const* d_in, const int* in_sizes, int n_in,
                              void* d_out, int out_size, void* d_ws, size_t ws_size,
                              hipStream_t stream) {
  const float* features = (const float*)d_in[0];
  const int* src2 = (const int*)d_in[1];
  const int* src1 = (const int*)d_in[3];
  const int* src0 = (const int*)d_in[5];
  const int* p21 = (const int*)d_in[7];
  const int* p10 = (const int*)d_in[8];
  const float* w_enc0 = (const float*)d_in[9];
  const float* b_enc0 = (const float*)d_in[10];
  const float* w_enc1 = (const float*)d_in[11];
  const float* b_enc1 = (const float*)d_in[12];
  const float* w_enc2 = (const float*)d_in[13];
  const float* b_enc2 = (const float*)d_in[14];
  const float* w_dec0 = (const float*)d_in[15];
  const float* b_dec0 = (const float*)d_in[16];
  const float* w_dec1 = (const float*)d_in[17];
  const float* b_dec1 = (const float*)d_in[18];

  // fp32 arrays
  float* f2  = (float*)d_ws;                    // [NV2,32]
  float* f1p = f2  + (size_t)NV2 * 32;          // [NV1,32]
  float* f1  = f1p + (size_t)NV1 * 32;          // [NV1,64]
  float* f0p = f1  + (size_t)NV1 * 64;          // [NV0,64]
  float* f0  = f0p + (size_t)NV0 * 64;          // [NV0,128]
  float* d1  = f0  + (size_t)NV0 * 128;         // [NV1,64]
  float* f32_end = d1 + (size_t)NV1 * 64;
  // bf16 shadow copies (gather sources)
  u16* featb = (u16*)f32_end;                   // [NV2,16]
  u16* f2b   = featb + (size_t)NV2 * 16;
  u16* f1pb  = f2b   + (size_t)NV2 * 32;
  u16* f1b   = f1pb  + (size_t)NV1 * 32;
  u16* f0pb  = f1b   + (size_t)NV1 * 64;
  u16* f0b   = f0pb  + (size_t)NV0 * 64;
  u16* d1b   = f0b   + (size_t)NV0 * 128;
  float* out = (float*)d_out;                   // [NV2,32]

  auto cdiv = [](long long a, long long b) { return (int)((a + b - 1) / b); };

  // bf16 copy of input features
  cvt_bf_k<<<cdiv((size_t)NV2 * 16, 256), 256, 0, stream>>>(features, featb, NV2 * 16);

  // encoder level 2
  edgeconv_k<16, 0, 32><<<cdiv(NV2, 16), 256, 0, stream>>>(
      features, featb, nullptr, nullptr, nullptr, src2, w_enc0, b_enc0, f2, f2b, NV2);

  // pool 2->1 (C=32)
  pool_init_k<32><<<cdiv((size_t)NV1 * 32, 256), 256, 0, stream>>>(f2, (u32*)f1p, NV1);
  pool_tail_k<32><<<cdiv((size_t)(NV2 - NV1) * 32, 256), 256, 0, stream>>>(
      f2, p21, (u32*)f1p, NV1, NV2);
  pool_decode_k<<<cdiv((size_t)NV1 * 32, 256), 256, 0, stream>>>((u32*)f1p, f1pb, NV1 * 32);

  // encoder level 1
  edgeconv_k<32, 0, 64><<<cdiv(NV1, 16), 256, 0, stream>>>(
      f1p, f1pb, nullptr, nullptr, nullptr, src1, w_enc1, b_enc1, f1, f1b, NV1);

  // pool 1->0 (C=64)
  pool_init_k<64><<<cdiv((size_t)NV0 * 64, 256), 256, 0, stream>>>(f1, (u32*)f0p, NV0);
  pool_tail_k<64><<<cdiv((size_t)(NV1 - NV0) * 64, 256), 256, 0, stream>>>(
      f1, p10, (u32*)f0p, NV0, NV1);
  pool_decode_k<<<cdiv((size_t)NV0 * 64, 256), 256, 0, stream>>>((u32*)f0p, f0pb, NV0 * 64);

  // encoder level 0
  edgeconv_k<64, 0, 128><<<cdiv(NV0, 16), 256, 0, stream>>>(
      f0p, f0pb, nullptr, nullptr, nullptr, src0, w_enc2, b_enc2, f0, f0b, NV0);

  // decoder level 1: u1 = concat(f0[p10], f1) -> d1
  edgeconv_k<128, 64, 64><<<cdiv(NV1, 16), 256, 0, stream>>>(
      f0, f0b, p10, f1, f1b, src1, w_dec0, b_dec0, d1, d1b, NV1);

  // decoder level 2: u2 = concat(d1[p21], f2) -> out
  edgeconv_k<64, 32, 32><<<cdiv(NV2, 16), 256, 0, stream>>>(
      d1, d1b, p21, f2, f2b, src2, w_dec1, b_dec1, out, nullptr, NV2);
}

// Round 3
// 522.818 us; speedup vs baseline: 1.2484x; 1.0769x over previous
//
#include <hip/hip_runtime.h>

#define NV2 163842
#define NV1 40962
#define NV0 10242

using u32 = unsigned int;
using u16 = unsigned short;

// ---------- float <-> orderable-uint encoding for atomic max ----------
__device__ __forceinline__ u32 fenc(float f) {
  u32 u = __float_as_uint(f);
  return (u & 0x80000000u) ? ~u : (u | 0x80000000u);
}
__device__ __forceinline__ float fdec(u32 k) {
  u32 u = (k & 0x80000000u) ? (k & 0x7FFFFFFFu) : ~k;
  return __uint_as_float(u);
}
// RNE float->bf16 bits
__device__ __forceinline__ u16 f2bf(float f) {
  u32 u = __float_as_uint(f);
  return (u16)((u + 0x7FFFu + ((u >> 16) & 1u)) >> 16);
}
__device__ __forceinline__ void unpack8(uint4 u, float* f) {
  f[0] = __uint_as_float(u.x << 16); f[1] = __uint_as_float(u.x & 0xFFFF0000u);
  f[2] = __uint_as_float(u.y << 16); f[3] = __uint_as_float(u.y & 0xFFFF0000u);
  f[4] = __uint_as_float(u.z << 16); f[5] = __uint_as_float(u.z & 0xFFFF0000u);
  f[6] = __uint_as_float(u.w << 16); f[7] = __uint_as_float(u.w & 0xFFFF0000u);
}

__global__ __launch_bounds__(256) void cvt_bf_k(const float* __restrict__ in,
                                                u16* __restrict__ out, int n) {
  int i = blockIdx.x * 256 + threadIdx.x;
  if (i < n) out[i] = f2bf(in[i]);
}

// ---------- pooling: identity-prefix init + tail-only atomic max ----------
template <int C>
__global__ __launch_bounds__(256) void pool_init_k(const float* __restrict__ in,
                                                   u32* __restrict__ out, int nparent) {
  int i = blockIdx.x * 256 + threadIdx.x;
  if (i < nparent * C) out[i] = fenc(in[i]);  // map[p] == p for p < nparent
}

template <int C>
__global__ __launch_bounds__(256) void pool_tail_k(const float* __restrict__ in,
                                                   const int* __restrict__ map,
                                                   u32* __restrict__ out,
                                                   int nparent, int nchild) {
  int i = blockIdx.x * 256 + threadIdx.x;
  int tail = (nchild - nparent) * C;
  if (i < tail) {
    int v = nparent + i / C, c = i % C;
    atomicMax(&out[(size_t)map[v] * C + c], fenc(in[(size_t)v * C + c]));
  }
}

__global__ __launch_bounds__(256) void pool_decode_k(u32* __restrict__ buf,
                                                     u16* __restrict__ outbf, int n) {
  int i = blockIdx.x * 256 + threadIdx.x;
  if (i < n) {
    float f = fdec(buf[i]);
    buf[i] = __float_as_uint(f);
    outbf[i] = f2bf(f);
  }
}

// ---------- materialize concat(A32[mapA], B32) as contiguous bf16 rows ----------
template <int CA, int CB>
__global__ __launch_bounds__(256) void mat_k(const float* __restrict__ A32,
                                             const int* __restrict__ mapA,
                                             const float* __restrict__ B32,
                                             u16* __restrict__ U, int nv) {
  constexpr int C = CA + CB;
  constexpr int Q = C / 4;
  int i = blockIdx.x * 256 + threadIdx.x;
  if (i >= nv * Q) return;
  int v = i / Q, c0 = (i % Q) * 4;
  float4 x;
  if (c0 < CA) x = *(const float4*)&A32[(size_t)mapA[v] * CA + c0];
  else         x = *(const float4*)&B32[(size_t)v * CB + (c0 - CA)];
  uint2 o;
  o.x = (u32)f2bf(x.x) | ((u32)f2bf(x.y) << 16);
  o.y = (u32)f2bf(x.z) | ((u32)f2bf(x.w) << 16);
  *(uint2*)&U[(size_t)v * C + c0] = o;
}

// ---------- fused EdgeConv: 16B bf16 gathers + linear + leaky ----------
// virtual input row v = U[v] (bf16); local read from A32 (fp32) when LF32.
template <int C, int COUT, int VB, bool LF32>
__global__ __launch_bounds__(256) void edgeconv_k(
    const float* __restrict__ A32, const u16* __restrict__ U,
    const int* __restrict__ src, const float* __restrict__ W,
    const float* __restrict__ bias, float* __restrict__ out, int nv) {
  constexpr int CIN = 2 * C;
  constexpr int Q = C / 8;          // 16B quads per row
  constexpr int TG = 256 / COUT;    // vertex groups in compute phase
  constexpr int VPT = VB / TG;      // vertices per thread

  __shared__ float xl[VB][CIN];

  const int t = threadIdx.x;
  const int vbase = blockIdx.x * VB;

  // ---- phase A: x = [local ; avg_nb - local] into LDS ----
  for (int idx = t; idx < VB * Q; idx += 256) {
    const int vi = idx / Q, q = idx % Q, c0 = q * 8;
    const int v = vbase + vi;
    if (v < nv) {
      float l[8];
      if constexpr (LF32) {
        float4 a = *(const float4*)&A32[(size_t)v * C + c0];
        float4 b = *(const float4*)&A32[(size_t)v * C + c0 + 4];
        l[0] = a.x; l[1] = a.y; l[2] = a.z; l[3] = a.w;
        l[4] = b.x; l[5] = b.y; l[6] = b.z; l[7] = b.w;
      } else {
        unpack8(*(const uint4*)&U[(size_t)v * C + c0], l);
      }
      float s[8] = {0.f, 0.f, 0.f, 0.f, 0.f, 0.f, 0.f, 0.f};
      const int* __restrict__ sp = src + (size_t)v * 6;
#pragma unroll
      for (int k = 0; k < 6; ++k) {
        float nb[8];
        unpack8(*(const uint4*)&U[(size_t)sp[k] * C + c0], nb);
#pragma unroll
        for (int j = 0; j < 8; ++j) s[j] += nb[j];
      }
      constexpr float inv6 = 1.f / 6.f;
      float d[8];
#pragma unroll
      for (int j = 0; j < 8; ++j) d[j] = s[j] * inv6 - l[j];
      *(float4*)&xl[vi][c0]       = make_float4(l[0], l[1], l[2], l[3]);
      *(float4*)&xl[vi][c0 + 4]   = make_float4(l[4], l[5], l[6], l[7]);
      *(float4*)&xl[vi][C + c0]     = make_float4(d[0], d[1], d[2], d[3]);
      *(float4*)&xl[vi][C + c0 + 4] = make_float4(d[4], d[5], d[6], d[7]);
    }
  }
  __syncthreads();

  // ---- phase B: y = W x + b, leaky 0.3 ----
  const int co = t % COUT;
  const int vig = t / COUT;
  float acc[VPT];
  const float b0 = bias[co];
#pragma unroll
  for (int j = 0; j < VPT; ++j) acc[j] = b0;
  const float* __restrict__ wr = W + (size_t)co * CIN;
  for (int ci = 0; ci < CIN; ci += 4) {
    float4 w4 = *(const float4*)&wr[ci];
#pragma unroll
    for (int j = 0; j < VPT; ++j) {
      float4 x4 = *(const float4*)&xl[vig * VPT + j][ci];
      acc[j] += w4.x * x4.x + w4.y * x4.y + w4.z * x4.z + w4.w * x4.w;
    }
  }
#pragma unroll
  for (int j = 0; j < VPT; ++j) {
    int v = vbase + vig * VPT + j;
    if (v < nv) {
      float y = acc[j];
      out[(size_t)v * COUT + co] = (y >= 0.f) ? y : 0.3f * y;
    }
  }
}

extern "C" void kernel_launch(void* const* d_in, const int* in_sizes, int n_in,
                              void* d_out, int out_size, void* d_ws, size_t ws_size,
                              hipStream_t stream) {
  const float* features = (const float*)d_in[0];
  const int* src2 = (const int*)d_in[1];
  const int* src1 = (const int*)d_in[3];
  const int* src0 = (const int*)d_in[5];
  const int* p21 = (const int*)d_in[7];
  const int* p10 = (const int*)d_in[8];
  const float* w_enc0 = (const float*)d_in[9];
  const float* b_enc0 = (const float*)d_in[10];
  const float* w_enc1 = (const float*)d_in[11];
  const float* b_enc1 = (const float*)d_in[12];
  const float* w_enc2 = (const float*)d_in[13];
  const float* b_enc2 = (const float*)d_in[14];
  const float* w_dec0 = (const float*)d_in[15];
  const float* b_dec0 = (const float*)d_in[16];
  const float* w_dec1 = (const float*)d_in[17];
  const float* b_dec1 = (const float*)d_in[18];

  // fp32 arrays
  float* f2  = (float*)d_ws;                    // [NV2,32]
  float* f1p = f2  + (size_t)NV2 * 32;          // [NV1,32]
  float* f1  = f1p + (size_t)NV1 * 32;          // [NV1,64]
  float* f0p = f1  + (size_t)NV1 * 64;          // [NV0,64]
  float* f0  = f0p + (size_t)NV0 * 64;          // [NV0,128]
  float* d1  = f0  + (size_t)NV0 * 128;         // [NV1,64]
  float* f32_end = d1 + (size_t)NV1 * 64;
  // bf16 pool. u2b aliases the whole pool start: featb/f1pb/f0pb/u1b are all
  // dead before u2b is written (enc0/enc1/enc2/dec0 completed).
  u16* bfpool = (u16*)f32_end;
  u16* featb = bfpool;                          // [NV2,16]
  u16* f1pb  = featb + (size_t)NV2 * 16;        // [NV1,32]
  u16* f0pb  = f1pb  + (size_t)NV1 * 32;        // [NV0,64]
  u16* u1b   = f0pb  + (size_t)NV0 * 64;        // [NV1,192]
  u16* u2b   = bfpool;                          // [NV2,96] (alias)
  float* out = (float*)d_out;                   // [NV2,32]

  auto cdiv = [](long long a, long long b) { return (int)((a + b - 1) / b); };

  // bf16 copy of input features
  cvt_bf_k<<<cdiv((size_t)NV2 * 16, 256), 256, 0, stream>>>(features, featb, NV2 * 16);

  // encoder level 2
  edgeconv_k<16, 32, 128, true><<<cdiv(NV2, 128), 256, 0, stream>>>(
      features, featb, src2, w_enc0, b_enc0, f2, NV2);

  // pool 2->1 (C=32)
  pool_init_k<32><<<cdiv((size_t)NV1 * 32, 256), 256, 0, stream>>>(f2, (u32*)f1p, NV1);
  pool_tail_k<32><<<cdiv((size_t)(NV2 - NV1) * 32, 256), 256, 0, stream>>>(
      f2, p21, (u32*)f1p, NV1, NV2);
  pool_decode_k<<<cdiv((size_t)NV1 * 32, 256), 256, 0, stream>>>((u32*)f1p, f1pb, NV1 * 32);

  // encoder level 1
  edgeconv_k<32, 64, 64, true><<<cdiv(NV1, 64), 256, 0, stream>>>(
      f1p, f1pb, src1, w_enc1, b_enc1, f1, NV1);

  // pool 1->0 (C=64)
  pool_init_k<64><<<cdiv((size_t)NV0 * 64, 256), 256, 0, stream>>>(f1, (u32*)f0p, NV0);
  pool_tail_k<64><<<cdiv((size_t)(NV1 - NV0) * 64, 256), 256, 0, stream>>>(
      f1, p10, (u32*)f0p, NV0, NV1);
  pool_decode_k<<<cdiv((size_t)NV0 * 64, 256), 256, 0, stream>>>((u32*)f0p, f0pb, NV0 * 64);

  // encoder level 0
  edgeconv_k<64, 128, 32, true><<<cdiv(NV0, 32), 256, 0, stream>>>(
      f0p, f0pb, src0, w_enc2, b_enc2, f0, NV0);

  // decoder level 1: u1 = concat(f0[p10], f1) materialized, then conv
  mat_k<128, 64><<<cdiv((size_t)NV1 * 48, 256), 256, 0, stream>>>(f0, p10, f1, u1b, NV1);
  edgeconv_k<192, 64, 16, false><<<cdiv(NV1, 16), 256, 0, stream>>>(
      nullptr, u1b, src1, w_dec0, b_dec0, d1, NV1);

  // decoder level 2: u2 = concat(d1[p21], f2) materialized, then conv
  mat_k<64, 32><<<cdiv((size_t)NV2 * 24, 256), 256, 0, stream>>>(d1, p21, f2, u2b, NV2);
  edgeconv_k<96, 32, 16, false><<<cdiv(NV2, 16), 256, 0, stream>>>(
      nullptr, u2b, src2, w_dec1, b_dec1, out, NV2);
}

// Round 4
// 235.214 us; speedup vs baseline: 2.7748x; 2.2227x over previous
//
#include <hip/hip_runtime.h>

#define NV2 163842
#define NV1 40962
#define NV0 10242

using u32 = unsigned int;
using u16 = unsigned short;

// ---------- float <-> orderable-uint encoding for atomic max ----------
__device__ __forceinline__ u32 fenc(float f) {
  u32 u = __float_as_uint(f);
  return (u & 0x80000000u) ? ~u : (u | 0x80000000u);
}
__device__ __forceinline__ float fdec(u32 k) {
  u32 u = (k & 0x80000000u) ? (k & 0x7FFFFFFFu) : ~k;
  return __uint_as_float(u);
}
// RNE float->bf16 bits
__device__ __forceinline__ u16 f2bf(float f) {
  u32 u = __float_as_uint(f);
  return (u16)((u + 0x7FFFu + ((u >> 16) & 1u)) >> 16);
}
__device__ __forceinline__ void unpack8(uint4 u, float* f) {
  f[0] = __uint_as_float(u.x << 16); f[1] = __uint_as_float(u.x & 0xFFFF0000u);
  f[2] = __uint_as_float(u.y << 16); f[3] = __uint_as_float(u.y & 0xFFFF0000u);
  f[4] = __uint_as_float(u.z << 16); f[5] = __uint_as_float(u.z & 0xFFFF0000u);
  f[6] = __uint_as_float(u.w << 16); f[7] = __uint_as_float(u.w & 0xFFFF0000u);
}

__global__ __launch_bounds__(256) void cvt_bf_k(const float* __restrict__ in,
                                                u16* __restrict__ out, int n) {
  int i = blockIdx.x * 256 + threadIdx.x;
  if (i < n) out[i] = f2bf(in[i]);
}

// ---------- pooling: identity-prefix init + tail-only atomic max ----------
template <int C>
__global__ __launch_bounds__(256) void pool_init_k(const float* __restrict__ in,
                                                   u32* __restrict__ out, int nparent) {
  int i = blockIdx.x * 256 + threadIdx.x;
  if (i < nparent * C) out[i] = fenc(in[i]);  // map[p] == p for p < nparent
}

template <int C>
__global__ __launch_bounds__(256) void pool_tail_k(const float* __restrict__ in,
                                                   const int* __restrict__ map,
                                                   u32* __restrict__ out,
                                                   int nparent, int nchild) {
  int i = blockIdx.x * 256 + threadIdx.x;
  int tail = (nchild - nparent) * C;
  if (i < tail) {
    int v = nparent + i / C, c = i % C;
    atomicMax(&out[(size_t)map[v] * C + c], fenc(in[(size_t)v * C + c]));
  }
}

__global__ __launch_bounds__(256) void pool_decode_k(u32* __restrict__ buf,
                                                     u16* __restrict__ outbf, int n) {
  int i = blockIdx.x * 256 + threadIdx.x;
  if (i < n) {
    float f = fdec(buf[i]);
    buf[i] = __float_as_uint(f);
    outbf[i] = f2bf(f);
  }
}

// ---------- materialize concat(A32[mapA], B32) as contiguous bf16 rows ----------
template <int CA, int CB>
__global__ __launch_bounds__(256) void mat_k(const float* __restrict__ A32,
                                             const int* __restrict__ mapA,
                                             const float* __restrict__ B32,
                                             u16* __restrict__ U, int nv) {
  constexpr int C = CA + CB;
  constexpr int Q = C / 4;
  int i = blockIdx.x * 256 + threadIdx.x;
  if (i >= nv * Q) return;
  int v = i / Q, c0 = (i % Q) * 4;
  float4 x;
  if (c0 < CA) x = *(const float4*)&A32[(size_t)mapA[v] * CA + c0];
  else         x = *(const float4*)&B32[(size_t)v * CB + (c0 - CA)];
  uint2 o;
  o.x = (u32)f2bf(x.x) | ((u32)f2bf(x.y) << 16);
  o.y = (u32)f2bf(x.z) | ((u32)f2bf(x.w) << 16);
  *(uint2*)&U[(size_t)v * C + c0] = o;
}

// ---------- encoder fused EdgeConv (gather-first; C < COUT) ----------
template <int C, int COUT, int VB, bool LF32>
__global__ __launch_bounds__(256) void edgeconv_k(
    const float* __restrict__ A32, const u16* __restrict__ U,
    const int* __restrict__ src, const float* __restrict__ W,
    const float* __restrict__ bias, float* __restrict__ out, int nv) {
  constexpr int CIN = 2 * C;
  constexpr int Q = C / 8;
  constexpr int TG = 256 / COUT;
  constexpr int VPT = VB / TG;

  __shared__ float xl[VB][CIN];

  const int t = threadIdx.x;
  const int vbase = blockIdx.x * VB;

  for (int idx = t; idx < VB * Q; idx += 256) {
    const int vi = idx / Q, q = idx % Q, c0 = q * 8;
    const int v = vbase + vi;
    if (v < nv) {
      float l[8];
      if constexpr (LF32) {
        float4 a = *(const float4*)&A32[(size_t)v * C + c0];
        float4 b = *(const float4*)&A32[(size_t)v * C + c0 + 4];
        l[0] = a.x; l[1] = a.y; l[2] = a.z; l[3] = a.w;
        l[4] = b.x; l[5] = b.y; l[6] = b.z; l[7] = b.w;
      } else {
        unpack8(*(const uint4*)&U[(size_t)v * C + c0], l);
      }
      float s[8] = {0.f, 0.f, 0.f, 0.f, 0.f, 0.f, 0.f, 0.f};
      const int* __restrict__ sp = src + (size_t)v * 6;
#pragma unroll
      for (int k = 0; k < 6; ++k) {
        float nb[8];
        unpack8(*(const uint4*)&U[(size_t)sp[k] * C + c0], nb);
#pragma unroll
        for (int j = 0; j < 8; ++j) s[j] += nb[j];
      }
      constexpr float inv6 = 1.f / 6.f;
      float d[8];
#pragma unroll
      for (int j = 0; j < 8; ++j) d[j] = s[j] * inv6 - l[j];
      *(float4*)&xl[vi][c0]       = make_float4(l[0], l[1], l[2], l[3]);
      *(float4*)&xl[vi][c0 + 4]   = make_float4(l[4], l[5], l[6], l[7]);
      *(float4*)&xl[vi][C + c0]     = make_float4(d[0], d[1], d[2], d[3]);
      *(float4*)&xl[vi][C + c0 + 4] = make_float4(d[4], d[5], d[6], d[7]);
    }
  }
  __syncthreads();

  const int co = t % COUT;
  const int vig = t / COUT;
  float acc[VPT];
  const float b0 = bias[co];
#pragma unroll
  for (int j = 0; j < VPT; ++j) acc[j] = b0;
  const float* __restrict__ wr = W + (size_t)co * CIN;
  for (int ci = 0; ci < CIN; ci += 4) {
    float4 w4 = *(const float4*)&wr[ci];
#pragma unroll
    for (int j = 0; j < VPT; ++j) {
      float4 x4 = *(const float4*)&xl[vig * VPT + j][ci];
      acc[j] += w4.x * x4.x + w4.y * x4.y + w4.z * x4.z + w4.w * x4.w;
    }
  }
#pragma unroll
  for (int j = 0; j < VPT; ++j) {
    int v = vbase + vig * VPT + j;
    if (v < nv) {
      float y = acc[j];
      out[(size_t)v * COUT + co] = (y >= 0.f) ? y : 0.3f * y;
    }
  }
}

// ---------- decoder: W' prep.  Wt[N=2*COUT][K=C] row-major, bf16 ----------
// cols j<COUT: W_nb row j;  j>=COUT: (W_loc - W_nb) row j-COUT.
template <int C, int COUT>
__global__ __launch_bounds__(256) void prep_w_k(const float* __restrict__ W,  // [COUT][2C]
                                                u16* __restrict__ Wt) {
  int i = blockIdx.x * 256 + threadIdx.x;
  if (i >= 2 * COUT * C) return;
  int j = i / C, k = i % C;
  float val;
  if (j < COUT) val = W[(size_t)j * 2 * C + C + k];
  else          val = W[(size_t)(j - COUT) * 2 * C + k] - W[(size_t)(j - COUT) * 2 * C + C + k];
  Wt[i] = f2bf(val);
}

// ---------- decoder: dense GEMM  [h|z] = U @ Wt^T  (MFMA bf16) ----------
typedef __attribute__((ext_vector_type(8))) short bf16x8;
typedef __attribute__((ext_vector_type(4))) float f32x4;

template <int K, int N, int COUT>  // N = 2*COUT
__global__ __launch_bounds__(256) void gemm_hz_k(
    const u16* __restrict__ U,   // [nv][K] bf16
    const u16* __restrict__ Wt,  // [N][K] bf16
    u16* __restrict__ h,         // [nv][COUT] bf16
    float* __restrict__ z,       // [nv][COUT] f32
    int nv) {
  constexpr int NT = N / 16;
  const int w = threadIdx.x >> 6, lane = threadIdx.x & 63;
  const int lr = lane & 15, lg = lane >> 4;
  const int vbase = blockIdx.x * 64 + w * 16;

  f32x4 acc[NT] = {};
  int arow = vbase + lr; if (arow >= nv) arow = nv - 1;
  const u16* __restrict__ up = U + (size_t)arow * K + lg * 8;
#pragma unroll
  for (int kt = 0; kt < K; kt += 32) {
    bf16x8 a = *(const bf16x8*)&up[kt];
#pragma unroll
    for (int nt = 0; nt < NT; ++nt) {
      bf16x8 b = *(const bf16x8*)&Wt[(size_t)(nt * 16 + lr) * K + kt + lg * 8];
      acc[nt] = __builtin_amdgcn_mfma_f32_16x16x32_bf16(a, b, acc[nt], 0, 0, 0);
    }
  }
  // D: col = lane&15 (n), row = (lane>>4)*4 + r (m)
#pragma unroll
  for (int nt = 0; nt < NT; ++nt) {
#pragma unroll
    for (int r = 0; r < 4; ++r) {
      int v = vbase + lg * 4 + r;
      if (v < nv) {
        int n = nt * 16 + lr;
        float val = acc[nt][r];
        if (n < COUT) h[(size_t)v * COUT + n] = f2bf(val);
        else          z[(size_t)v * COUT + (n - COUT)] = val;
      }
    }
  }
}

// ---------- decoder: combine  y = leaky(z + avg_nb(h) + b) ----------
template <int COUT>
__global__ __launch_bounds__(256) void combine_k(
    const u16* __restrict__ h, const float* __restrict__ z,
    const int* __restrict__ src, const float* __restrict__ bias,
    float* __restrict__ out, int nv) {
  constexpr int TPV = COUT / 8;
  int gid = blockIdx.x * 256 + threadIdx.x;
  if (gid >= nv * TPV) return;
  int v = gid / TPV, c0 = (gid % TPV) * 8;
  const int* __restrict__ sp = src + (size_t)v * 6;
  float s[8] = {0.f, 0.f, 0.f, 0.f, 0.f, 0.f, 0.f, 0.f};
#pragma unroll
  for (int k = 0; k < 6; ++k) {
    float nb[8];
    unpack8(*(const uint4*)&h[(size_t)sp[k] * COUT + c0], nb);
#pragma unroll
    for (int j = 0; j < 8; ++j) s[j] += nb[j];
  }
  constexpr float inv6 = 1.f / 6.f;
  float4 z0 = *(const float4*)&z[(size_t)v * COUT + c0];
  float4 z1 = *(const float4*)&z[(size_t)v * COUT + c0 + 4];
  float4 b0 = *(const float4*)&bias[c0];
  float4 b1 = *(const float4*)&bias[c0 + 4];
  float y[8];
  y[0] = z0.x + s[0] * inv6 + b0.x; y[1] = z0.y + s[1] * inv6 + b0.y;
  y[2] = z0.z + s[2] * inv6 + b0.z; y[3] = z0.w + s[3] * inv6 + b0.w;
  y[4] = z1.x + s[4] * inv6 + b1.x; y[5] = z1.y + s[5] * inv6 + b1.y;
  y[6] = z1.z + s[6] * inv6 + b1.z; y[7] = z1.w + s[7] * inv6 + b1.w;
#pragma unroll
  for (int j = 0; j < 8; ++j) y[j] = (y[j] >= 0.f) ? y[j] : 0.3f * y[j];
  *(float4*)&out[(size_t)v * COUT + c0]     = make_float4(y[0], y[1], y[2], y[3]);
  *(float4*)&out[(size_t)v * COUT + c0 + 4] = make_float4(y[4], y[5], y[6], y[7]);
}

extern "C" void kernel_launch(void* const* d_in, const int* in_sizes, int n_in,
                              void* d_out, int out_size, void* d_ws, size_t ws_size,
                              hipStream_t stream) {
  const float* features = (const float*)d_in[0];
  const int* src2 = (const int*)d_in[1];
  const int* src1 = (const int*)d_in[3];
  const int* src0 = (const int*)d_in[5];
  const int* p21 = (const int*)d_in[7];
  const int* p10 = (const int*)d_in[8];
  const float* w_enc0 = (const float*)d_in[9];
  const float* b_enc0 = (const float*)d_in[10];
  const float* w_enc1 = (const float*)d_in[11];
  const float* b_enc1 = (const float*)d_in[12];
  const float* w_enc2 = (const float*)d_in[13];
  const float* b_enc2 = (const float*)d_in[14];
  const float* w_dec0 = (const float*)d_in[15];
  const float* b_dec0 = (const float*)d_in[16];
  const float* w_dec1 = (const float*)d_in[17];
  const float* b_dec1 = (const float*)d_in[18];

  // ---- fp32 block ----
  float* f2  = (float*)d_ws;                    // [NV2,32]
  float* f1p = f2  + (size_t)NV2 * 32;          // [NV1,32]  (dead after enc1 -> h1b)
  float* f1  = f1p + (size_t)NV1 * 32;          // [NV1,64]
  float* f0p = f1  + (size_t)NV1 * 64;          // [NV0,64]
  float* f0  = f0p + (size_t)NV0 * 64;          // [NV0,128]
  float* d1  = f0  + (size_t)NV0 * 128;         // [NV1,64]
  float* f32_end = d1 + (size_t)NV1 * 64;
  // z2 [NV2,32] aliases f1..d1 (all dead when gemm dec1 writes it)
  float* z2 = f1;
  // h1b [NV1,64] bf16 aliases f1p (same byte size; f1p dead after enc1)
  u16* h1b = (u16*)f1p;
  // ---- z1 [NV1,64] f32 (fresh); h2b aliases z1 (z1 dead after combine dec0) ----
  float* z1 = f32_end;
  u16* h2b = (u16*)z1;                          // [NV2,32] bf16, same 10.5 MB
  float* z1_end = z1 + (size_t)NV1 * 64;
  // ---- bf16 pool ----
  u16* bfpool = (u16*)z1_end;
  u16* featb = bfpool;                          // [NV2,16]
  u16* f1pb  = featb + (size_t)NV2 * 16;        // [NV1,32]
  u16* f0pb  = f1pb  + (size_t)NV1 * 32;        // [NV0,64]
  u16* u1b   = f0pb  + (size_t)NV0 * 64;        // [NV1,192]
  u16* u2b   = bfpool;                          // [NV2,96] aliases pool (all dead by then)
  u16* pool_end = bfpool + (size_t)NV2 * 96;    // u2b is the largest pool occupant
  // ---- Wt ----
  u16* Wt0 = pool_end;                          // [128,192]
  u16* Wt1 = Wt0 + 128 * 192;                   // [64,96]
  float* out = (float*)d_out;                   // [NV2,32]

  auto cdiv = [](long long a, long long b) { return (int)((a + b - 1) / b); };

  // weight prep (no pipeline deps)
  prep_w_k<192, 64><<<cdiv(128 * 192, 256), 256, 0, stream>>>(w_dec0, Wt0);
  prep_w_k<96, 32><<<cdiv(64 * 96, 256), 256, 0, stream>>>(w_dec1, Wt1);

  // bf16 copy of input features
  cvt_bf_k<<<cdiv((size_t)NV2 * 16, 256), 256, 0, stream>>>(features, featb, NV2 * 16);

  // encoder level 2
  edgeconv_k<16, 32, 128, true><<<cdiv(NV2, 128), 256, 0, stream>>>(
      features, featb, src2, w_enc0, b_enc0, f2, NV2);

  // pool 2->1 (C=32)
  pool_init_k<32><<<cdiv((size_t)NV1 * 32, 256), 256, 0, stream>>>(f2, (u32*)f1p, NV1);
  pool_tail_k<32><<<cdiv((size_t)(NV2 - NV1) * 32, 256), 256, 0, stream>>>(
      f2, p21, (u32*)f1p, NV1, NV2);
  pool_decode_k<<<cdiv((size_t)NV1 * 32, 256), 256, 0, stream>>>((u32*)f1p, f1pb, NV1 * 32);

  // encoder level 1
  edgeconv_k<32, 64, 64, true><<<cdiv(NV1, 64), 256, 0, stream>>>(
      f1p, f1pb, src1, w_enc1, b_enc1, f1, NV1);

  // pool 1->0 (C=64)
  pool_init_k<64><<<cdiv((size_t)NV0 * 64, 256), 256, 0, stream>>>(f1, (u32*)f0p, NV0);
  pool_tail_k<64><<<cdiv((size_t)(NV1 - NV0) * 64, 256), 256, 0, stream>>>(
      f1, p10, (u32*)f0p, NV0, NV1);
  pool_decode_k<<<cdiv((size_t)NV0 * 64, 256), 256, 0, stream>>>((u32*)f0p, f0pb, NV0 * 64);

  // encoder level 0
  edgeconv_k<64, 128, 32, true><<<cdiv(NV0, 32), 256, 0, stream>>>(
      f0p, f0pb, src0, w_enc2, b_enc2, f0, NV0);

  // ---- decoder level 1: u1 = concat(f0[p10], f1);  [h1|z1] = u1 @ Wt0^T ----
  mat_k<128, 64><<<cdiv((size_t)NV1 * 48, 256), 256, 0, stream>>>(f0, p10, f1, u1b, NV1);
  gemm_hz_k<192, 128, 64><<<cdiv(NV1, 64), 256, 0, stream>>>(u1b, Wt0, h1b, z1, NV1);
  combine_k<64><<<cdiv((size_t)NV1 * 8, 256), 256, 0, stream>>>(
      h1b, z1, src1, b_dec0, d1, NV1);

  // ---- decoder level 2: u2 = concat(d1[p21], f2);  [h2|z2] = u2 @ Wt1^T ----
  mat_k<64, 32><<<cdiv((size_t)NV2 * 24, 256), 256, 0, stream>>>(d1, p21, f2, u2b, NV2);
  gemm_hz_k<96, 64, 32><<<cdiv(NV2, 64), 256, 0, stream>>>(u2b, Wt1, h2b, z2, NV2);
  combine_k<32><<<cdiv((size_t)NV2 * 4, 256), 256, 0, stream>>>(
      h2b, z2, src2, b_dec1, out, NV2);
}

// Round 5
// 171.355 us; speedup vs baseline: 3.8089x; 1.3727x over previous
//
#include <hip/hip_runtime.h>

#define NV2 163842
#define NV1 40962
#define NV0 10242

using u32 = unsigned int;
using u16 = unsigned short;

typedef __attribute__((ext_vector_type(8))) short bf16x8;
typedef __attribute__((ext_vector_type(4))) float f32x4;

// ---------- float <-> orderable-uint encoding for atomic max ----------
__device__ __forceinline__ u32 fenc(float f) {
  u32 u = __float_as_uint(f);
  return (u & 0x80000000u) ? ~u : (u | 0x80000000u);
}
__device__ __forceinline__ float fdec(u32 k) {
  u32 u = (k & 0x80000000u) ? (k & 0x7FFFFFFFu) : ~k;
  return __uint_as_float(u);
}
// RNE float->bf16 bits
__device__ __forceinline__ u16 f2bf(float f) {
  u32 u = __float_as_uint(f);
  return (u16)((u + 0x7FFFu + ((u >> 16) & 1u)) >> 16);
}
__device__ __forceinline__ void unpack8(uint4 u, float* f) {
  f[0] = __uint_as_float(u.x << 16); f[1] = __uint_as_float(u.x & 0xFFFF0000u);
  f[2] = __uint_as_float(u.y << 16); f[3] = __uint_as_float(u.y & 0xFFFF0000u);
  f[4] = __uint_as_float(u.z << 16); f[5] = __uint_as_float(u.z & 0xFFFF0000u);
  f[6] = __uint_as_float(u.w << 16); f[7] = __uint_as_float(u.w & 0xFFFF0000u);
}
__device__ __forceinline__ uint4 pack8(const float* f) {
  uint4 o;
  o.x = (u32)f2bf(f[0]) | ((u32)f2bf(f[1]) << 16);
  o.y = (u32)f2bf(f[2]) | ((u32)f2bf(f[3]) << 16);
  o.z = (u32)f2bf(f[4]) | ((u32)f2bf(f[5]) << 16);
  o.w = (u32)f2bf(f[6]) | ((u32)f2bf(f[7]) << 16);
  return o;
}

__global__ __launch_bounds__(256) void cvt_bf_k(const float* __restrict__ in,
                                                u16* __restrict__ out, int n) {
  int i = blockIdx.x * 256 + threadIdx.x;
  if (i < n) out[i] = f2bf(in[i]);
}

// ---------- pooling: identity-prefix init + tail-only atomic max ----------
template <int C>
__global__ __launch_bounds__(256) void pool_init_k(const float* __restrict__ in,
                                                   u32* __restrict__ out, int nparent) {
  int i = blockIdx.x * 256 + threadIdx.x;
  if (i < nparent * C) out[i] = fenc(in[i]);  // map[p] == p for p < nparent
}

template <int C>
__global__ __launch_bounds__(256) void pool_tail_k(const float* __restrict__ in,
                                                   const int* __restrict__ map,
                                                   u32* __restrict__ out,
                                                   int nparent, int nchild) {
  int i = blockIdx.x * 256 + threadIdx.x;
  int tail = (nchild - nparent) * C;
  if (i < tail) {
    int v = nparent + i / C, c = i % C;
    atomicMax(&out[(size_t)map[v] * C + c], fenc(in[(size_t)v * C + c]));
  }
}

__global__ __launch_bounds__(256) void pool_decode_k(const u32* __restrict__ buf,
                                                     u16* __restrict__ outbf, int n) {
  int i = blockIdx.x * 256 + threadIdx.x;
  if (i < n) outbf[i] = f2bf(fdec(buf[i]));
}

// ---------- gather-average: g[v] = avg6(fb[src[v,k]])  (bf16 in/out) ----------
template <int C>
__global__ __launch_bounds__(256) void gather_avg_k(const u16* __restrict__ fb,
                                                    const int* __restrict__ src,
                                                    u16* __restrict__ g, int nv) {
  constexpr int TPV = C / 8;
  int gid = blockIdx.x * 256 + threadIdx.x;
  if (gid >= nv * TPV) return;
  int v = gid / TPV, c0 = (gid % TPV) * 8;
  const int* __restrict__ sp = src + (size_t)v * 6;
  float s[8] = {0.f, 0.f, 0.f, 0.f, 0.f, 0.f, 0.f, 0.f};
#pragma unroll
  for (int k = 0; k < 6; ++k) {
    float nb[8];
    unpack8(*(const uint4*)&fb[(size_t)sp[k] * C + c0], nb);
#pragma unroll
    for (int j = 0; j < 8; ++j) s[j] += nb[j];
  }
  constexpr float inv6 = 1.f / 6.f;
#pragma unroll
  for (int j = 0; j < 8; ++j) s[j] *= inv6;
  *(uint4*)&g[(size_t)v * C + c0] = pack8(s);
}

// ---------- weight preps (bf16, row-major [N][K]) ----------
// Encoder: y = (Wl-Wn) f + Wn g ; Wt[j][k] = (k<C) ? W[j][k]-W[j][k+C] : W[j][k]
template <int C, int COUT>
__global__ __launch_bounds__(256) void prep_w_enc_k(const float* __restrict__ W,
                                                    u16* __restrict__ Wt) {
  int i = blockIdx.x * 256 + threadIdx.x;
  if (i >= COUT * 2 * C) return;
  int j = i / (2 * C), k = i % (2 * C);
  float val = W[(size_t)j * 2 * C + k];
  if (k < C) val -= W[(size_t)j * 2 * C + k + C];
  Wt[i] = f2bf(val);
}
// Decoder: rows j<COUT: Wn ; j>=COUT: Wl-Wn   (h = Wn u, z = (Wl-Wn) u)
template <int C, int COUT>
__global__ __launch_bounds__(256) void prep_w_dec_k(const float* __restrict__ W,
                                                    u16* __restrict__ Wt) {
  int i = blockIdx.x * 256 + threadIdx.x;
  if (i >= 2 * COUT * C) return;
  int j = i / C, k = i % C;
  float val;
  if (j < COUT) val = W[(size_t)j * 2 * C + C + k];
  else          val = W[(size_t)(j - COUT) * 2 * C + k] - W[(size_t)(j - COUT) * 2 * C + C + k];
  Wt[i] = f2bf(val);
}

// ---------- encoder GEMM: y = leaky([fb|g] @ Wt^T + b) ----------
template <int C, int COUT, bool OUT32, bool OUTB>
__global__ __launch_bounds__(256) void gemm_enc_k(
    const u16* __restrict__ fb, const u16* __restrict__ g,
    const u16* __restrict__ Wt, const float* __restrict__ bias,
    float* __restrict__ out32, u16* __restrict__ outb, int nv) {
  constexpr int K = 2 * C;
  constexpr int NT = COUT / 16;
  const int w = threadIdx.x >> 6, lane = threadIdx.x & 63;
  const int lr = lane & 15, lg = lane >> 4;
  const int vbase = blockIdx.x * 64 + w * 16;
  int arow = vbase + lr; if (arow >= nv) arow = nv - 1;

  f32x4 acc[NT] = {};
#pragma unroll
  for (int kt = 0; kt < K; kt += 32) {
    int k = kt + lg * 8;
    bf16x8 a = (k < C) ? *(const bf16x8*)&fb[(size_t)arow * C + k]
                       : *(const bf16x8*)&g[(size_t)arow * C + (k - C)];
#pragma unroll
    for (int nt = 0; nt < NT; ++nt) {
      bf16x8 b = *(const bf16x8*)&Wt[(size_t)(nt * 16 + lr) * K + kt + lg * 8];
      acc[nt] = __builtin_amdgcn_mfma_f32_16x16x32_bf16(a, b, acc[nt], 0, 0, 0);
    }
  }
#pragma unroll
  for (int nt = 0; nt < NT; ++nt) {
#pragma unroll
    for (int r = 0; r < 4; ++r) {
      int v = vbase + lg * 4 + r;
      if (v < nv) {
        int n = nt * 16 + lr;
        float y = acc[nt][r] + bias[n];
        y = (y >= 0.f) ? y : 0.3f * y;
        if constexpr (OUT32) out32[(size_t)v * COUT + n] = y;
        if constexpr (OUTB)  outb[(size_t)v * COUT + n] = f2bf(y);
      }
    }
  }
}

// ---------- decoder GEMM (concat fused): [h|z] = [Ab[map[v]] | Bb[v]] @ Wt^T ----------
template <int CA, int CB, int COUT>
__global__ __launch_bounds__(256) void gemm_dec_k(
    const u16* __restrict__ Ab, const int* __restrict__ map,
    const u16* __restrict__ Bb, const u16* __restrict__ Wt,
    u16* __restrict__ h, float* __restrict__ z, int nv) {
  constexpr int K = CA + CB;
  constexpr int N = 2 * COUT;
  constexpr int NT = N / 16;
  const int w = threadIdx.x >> 6, lane = threadIdx.x & 63;
  const int lr = lane & 15, lg = lane >> 4;
  const int vbase = blockIdx.x * 64 + w * 16;
  int arow = vbase + lr; if (arow >= nv) arow = nv - 1;
  const int m = map[arow];

  f32x4 acc[NT] = {};
#pragma unroll
  for (int kt = 0; kt < K; kt += 32) {
    int k = kt + lg * 8;
    bf16x8 a = (k < CA) ? *(const bf16x8*)&Ab[(size_t)m * CA + k]
                        : *(const bf16x8*)&Bb[(size_t)arow * CB + (k - CA)];
#pragma unroll
    for (int nt = 0; nt < NT; ++nt) {
      bf16x8 b = *(const bf16x8*)&Wt[(size_t)(nt * 16 + lr) * K + kt + lg * 8];
      acc[nt] = __builtin_amdgcn_mfma_f32_16x16x32_bf16(a, b, acc[nt], 0, 0, 0);
    }
  }
#pragma unroll
  for (int nt = 0; nt < NT; ++nt) {
#pragma unroll
    for (int r = 0; r < 4; ++r) {
      int v = vbase + lg * 4 + r;
      if (v < nv) {
        int n = nt * 16 + lr;
        float val = acc[nt][r];
        if (n < COUT) h[(size_t)v * COUT + n] = f2bf(val);
        else          z[(size_t)v * COUT + (n - COUT)] = val;
      }
    }
  }
}

// ---------- decoder combine: y = leaky(z + avg6(h) + b) ----------
template <int COUT, bool OUT32, bool OUTB>
__global__ __launch_bounds__(256) void combine_k(
    const u16* __restrict__ h, const float* __restrict__ z,
    const int* __restrict__ src, const float* __restrict__ bias,
    float* __restrict__ out32, u16* __restrict__ outb, int nv) {
  constexpr int TPV = COUT / 8;
  int gid = blockIdx.x * 256 + threadIdx.x;
  if (gid >= nv * TPV) return;
  int v = gid / TPV, c0 = (gid % TPV) * 8;
  const int* __restrict__ sp = src + (size_t)v * 6;
  float s[8] = {0.f, 0.f, 0.f, 0.f, 0.f, 0.f, 0.f, 0.f};
#pragma unroll
  for (int k = 0; k < 6; ++k) {
    float nb[8];
    unpack8(*(const uint4*)&h[(size_t)sp[k] * COUT + c0], nb);
#pragma unroll
    for (int j = 0; j < 8; ++j) s[j] += nb[j];
  }
  constexpr float inv6 = 1.f / 6.f;
  float4 z0 = *(const float4*)&z[(size_t)v * COUT + c0];
  float4 z1 = *(const float4*)&z[(size_t)v * COUT + c0 + 4];
  float4 b0 = *(const float4*)&bias[c0];
  float4 b1 = *(const float4*)&bias[c0 + 4];
  float y[8];
  y[0] = z0.x + s[0] * inv6 + b0.x; y[1] = z0.y + s[1] * inv6 + b0.y;
  y[2] = z0.z + s[2] * inv6 + b0.z; y[3] = z0.w + s[3] * inv6 + b0.w;
  y[4] = z1.x + s[4] * inv6 + b1.x; y[5] = z1.y + s[5] * inv6 + b1.y;
  y[6] = z1.z + s[6] * inv6 + b1.z; y[7] = z1.w + s[7] * inv6 + b1.w;
#pragma unroll
  for (int j = 0; j < 8; ++j) y[j] = (y[j] >= 0.f) ? y[j] : 0.3f * y[j];
  if constexpr (OUT32) {
    *(float4*)&out32[(size_t)v * COUT + c0]     = make_float4(y[0], y[1], y[2], y[3]);
    *(float4*)&out32[(size_t)v * COUT + c0 + 4] = make_float4(y[4], y[5], y[6], y[7]);
  }
  if constexpr (OUTB) *(uint4*)&outb[(size_t)v * COUT + c0] = pack8(y);
}

extern "C" void kernel_launch(void* const* d_in, const int* in_sizes, int n_in,
                              void* d_out, int out_size, void* d_ws, size_t ws_size,
                              hipStream_t stream) {
  const float* features = (const float*)d_in[0];
  const int* src2 = (const int*)d_in[1];
  const int* src1 = (const int*)d_in[3];
  const int* src0 = (const int*)d_in[5];
  const int* p21 = (const int*)d_in[7];
  const int* p10 = (const int*)d_in[8];
  const float* w_enc0 = (const float*)d_in[9];
  const float* b_enc0 = (const float*)d_in[10];
  const float* w_enc1 = (const float*)d_in[11];
  const float* b_enc1 = (const float*)d_in[12];
  const float* w_enc2 = (const float*)d_in[13];
  const float* b_enc2 = (const float*)d_in[14];
  const float* w_dec0 = (const float*)d_in[15];
  const float* b_dec0 = (const float*)d_in[16];
  const float* w_dec1 = (const float*)d_in[17];
  const float* b_dec1 = (const float*)d_in[18];

  // ---- workspace layout (fresh ~76 MB; aliases noted) ----
  float* f2   = (float*)d_ws;                       // [NV2,32] f32   (z2 aliases)
  float* f1   = f2 + (size_t)NV2 * 32;              // [NV1,64] f32   (z1 aliases)
  u32*  pb1   = (u32*)(f1 + (size_t)NV1 * 64);      // [NV1,32] u32   (h1b aliases)
  u16*  featb = (u16*)(pb1 + (size_t)NV1 * 32);     // [NV2,16] bf16  (h2b aliases featb+g0)
  u16*  g0    = featb + (size_t)NV2 * 16;           // [NV2,16]
  u32*  pb0   = (u32*)(g0 + (size_t)NV2 * 16);      // [NV0,64] u32
  u16*  f0pb  = (u16*)(pb0 + (size_t)NV0 * 64);     // [NV0,64]
  u16*  g2    = f0pb + (size_t)NV0 * 64;            // [NV0,64]
  u16*  f1pb  = g2 + (size_t)NV0 * 64;              // [NV1,32]  (d1b aliases f1pb+g1)
  u16*  g1    = f1pb + (size_t)NV1 * 32;            // [NV1,32]
  u16*  f2b   = g1 + (size_t)NV1 * 32;              // [NV2,32]
  u16*  f1b   = f2b + (size_t)NV2 * 32;             // [NV1,64]
  u16*  f0b   = f1b + (size_t)NV1 * 64;             // [NV0,128]
  u16*  We0   = f0b + (size_t)NV0 * 128;            // [32,32]
  u16*  We1   = We0 + 32 * 32;                      // [64,64]
  u16*  We2   = We1 + 64 * 64;                      // [128,128]
  u16*  Wd0   = We2 + 128 * 128;                    // [128,192]
  u16*  Wd1   = Wd0 + 128 * 192;                    // [64,96]
  // aliases (lifetimes disjoint):
  float* z1  = f1;            // f1 dead after pool 1->0
  float* z2  = f2;            // f2 dead after pool 2->1
  u16*  h1b  = (u16*)pb1;     // pb1 dead after decode1
  u16*  h2b  = featb;         // featb+g0 dead after enc0 gemm
  u16*  d1b  = f1pb;          // f1pb+g1 dead after enc1 gemm
  float* out = (float*)d_out; // [NV2,32]

  auto cdiv = [](long long a, long long b) { return (int)((a + b - 1) / b); };

  // ---- weight preps (no deps) ----
  prep_w_enc_k<16, 32><<<cdiv(32 * 32, 256), 256, 0, stream>>>(w_enc0, We0);
  prep_w_enc_k<32, 64><<<cdiv(64 * 64, 256), 256, 0, stream>>>(w_enc1, We1);
  prep_w_enc_k<64, 128><<<cdiv(128 * 128, 256), 256, 0, stream>>>(w_enc2, We2);
  prep_w_dec_k<192, 64><<<cdiv(128 * 192, 256), 256, 0, stream>>>(w_dec0, Wd0);
  prep_w_dec_k<96, 32><<<cdiv(64 * 96, 256), 256, 0, stream>>>(w_dec1, Wd1);

  // ---- input to bf16 ----
  cvt_bf_k<<<cdiv((size_t)NV2 * 16, 256), 256, 0, stream>>>(features, featb, NV2 * 16);

  // ---- encoder level 2: gather + GEMM ----
  gather_avg_k<16><<<cdiv((size_t)NV2 * 2, 256), 256, 0, stream>>>(featb, src2, g0, NV2);
  gemm_enc_k<16, 32, true, true><<<cdiv(NV2, 64), 256, 0, stream>>>(
      featb, g0, We0, b_enc0, f2, f2b, NV2);

  // ---- pool 2->1 (C=32) ----
  pool_init_k<32><<<cdiv((size_t)NV1 * 32, 256), 256, 0, stream>>>(f2, pb1, NV1);
  pool_tail_k<32><<<cdiv((size_t)(NV2 - NV1) * 32, 256), 256, 0, stream>>>(
      f2, p21, pb1, NV1, NV2);
  pool_decode_k<<<cdiv((size_t)NV1 * 32, 256), 256, 0, stream>>>(pb1, f1pb, NV1 * 32);

  // ---- encoder level 1 ----
  gather_avg_k<32><<<cdiv((size_t)NV1 * 4, 256), 256, 0, stream>>>(f1pb, src1, g1, NV1);
  gemm_enc_k<32, 64, true, true><<<cdiv(NV1, 64), 256, 0, stream>>>(
      f1pb, g1, We1, b_enc1, f1, f1b, NV1);

  // ---- pool 1->0 (C=64) ----
  pool_init_k<64><<<cdiv((size_t)NV0 * 64, 256), 256, 0, stream>>>(f1, pb0, NV0);
  pool_tail_k<64><<<cdiv((size_t)(NV1 - NV0) * 64, 256), 256, 0, stream>>>(
      f1, p10, pb0, NV0, NV1);
  pool_decode_k<<<cdiv((size_t)NV0 * 64, 256), 256, 0, stream>>>(pb0, f0pb, NV0 * 64);

  // ---- encoder level 0 (bf16 out only) ----
  gather_avg_k<64><<<cdiv((size_t)NV0 * 8, 256), 256, 0, stream>>>(f0pb, src0, g2, NV0);
  gemm_enc_k<64, 128, false, true><<<cdiv(NV0, 64), 256, 0, stream>>>(
      f0pb, g2, We2, b_enc2, nullptr, f0b, NV0);

  // ---- decoder level 1: u1 = [f0b[p10] | f1b] fused into GEMM ----
  gemm_dec_k<128, 64, 64><<<cdiv(NV1, 64), 256, 0, stream>>>(
      f0b, p10, f1b, Wd0, h1b, z1, NV1);
  combine_k<64, false, true><<<cdiv((size_t)NV1 * 8, 256), 256, 0, stream>>>(
      h1b, z1, src1, b_dec0, nullptr, d1b, NV1);

  // ---- decoder level 2: u2 = [d1b[p21] | f2b] fused into GEMM ----
  gemm_dec_k<64, 32, 32><<<cdiv(NV2, 64), 256, 0, stream>>>(
      d1b, p21, f2b, Wd1, h2b, z2, NV2);
  combine_k<32, true, false><<<cdiv((size_t)NV2 * 4, 256), 256, 0, stream>>>(
      h2b, z2, src2, b_dec1, out, nullptr, NV2);
}

// Round 6
// 136.609 us; speedup vs baseline: 4.7777x; 1.2543x over previous
//
#include <hip/hip_runtime.h>

#define NV2 163842
#define NV1 40962
#define NV0 10242

using u32 = unsigned int;
using u16 = unsigned short;

typedef __attribute__((ext_vector_type(8))) short bf16x8;
typedef __attribute__((ext_vector_type(4))) float f32x4;

// RNE float->bf16 bits
__device__ __forceinline__ u16 f2bf(float f) {
  u32 u = __float_as_uint(f);
  return (u16)((u + 0x7FFFu + ((u >> 16) & 1u)) >> 16);
}
__device__ __forceinline__ void unpack8(uint4 u, float* f) {
  f[0] = __uint_as_float(u.x << 16); f[1] = __uint_as_float(u.x & 0xFFFF0000u);
  f[2] = __uint_as_float(u.y << 16); f[3] = __uint_as_float(u.y & 0xFFFF0000u);
  f[4] = __uint_as_float(u.z << 16); f[5] = __uint_as_float(u.z & 0xFFFF0000u);
  f[6] = __uint_as_float(u.w << 16); f[7] = __uint_as_float(u.w & 0xFFFF0000u);
}
__device__ __forceinline__ uint4 pack8(const float* f) {
  uint4 o;
  o.x = (u32)f2bf(f[0]) | ((u32)f2bf(f[1]) << 16);
  o.y = (u32)f2bf(f[2]) | ((u32)f2bf(f[3]) << 16);
  o.z = (u32)f2bf(f[4]) | ((u32)f2bf(f[5]) << 16);
  o.w = (u32)f2bf(f[6]) | ((u32)f2bf(f[7]) << 16);
  return o;
}
// orderable 16-bit encoding of bf16 bits (for atomicMax pooling in high half of u32)
__device__ __forceinline__ u16 enc16(u16 h) {
  return (h & 0x8000u) ? (u16)~h : (u16)(h | 0x8000u);
}
__device__ __forceinline__ u16 dec16(u16 e) {
  return (e & 0x8000u) ? (u16)(e & 0x7FFFu) : (u16)~e;
}

// ---------- weight transform values ----------
// Encoder GEMM A = [f | g]:  Wt[j][k] = (k<C) ? W[j][k]-W[j][C+k] : W[j][k]
__device__ __forceinline__ float enc_w(const float* __restrict__ W, int C, int i) {
  int j = i / (2 * C), k = i % (2 * C);
  float v = W[(size_t)j * 2 * C + k];
  if (k < C) v -= W[(size_t)j * 2 * C + C + k];
  return v;
}
// Decoder: rows j<COUT: Wn ; rows j>=COUT: Wl-Wn
__device__ __forceinline__ float dec_w(const float* __restrict__ W, int C, int COUT, int i) {
  int j = i / C, k = i % C;
  if (j < COUT) return W[(size_t)j * 2 * C + C + k];
  return W[(size_t)(j - COUT) * 2 * C + k] - W[(size_t)(j - COUT) * 2 * C + C + k];
}

// ---------- one-shot prep: cvt input to bf16, zero pool buffers, 5 weight preps ----------
__global__ __launch_bounds__(256) void prep_all_k(
    const float* __restrict__ features, u16* __restrict__ featb,
    u32* __restrict__ pb1, u32* __restrict__ pb0,
    const float* __restrict__ w_enc0, u16* __restrict__ We0,
    const float* __restrict__ w_enc1, u16* __restrict__ We1,
    const float* __restrict__ w_enc2, u16* __restrict__ We2,
    const float* __restrict__ w_dec0, u16* __restrict__ Wd0,
    const float* __restrict__ w_dec1, u16* __restrict__ Wd1) {
  long i = (long)blockIdx.x * 256 + threadIdx.x;
  const long n_cvt = (long)NV2 * 16;
  if (i < n_cvt) { featb[i] = f2bf(features[i]); return; }
  i -= n_cvt;
  const long n_pb1 = (long)NV1 * 32;
  if (i < n_pb1) { pb1[i] = 0u; return; }
  i -= n_pb1;
  const long n_pb0 = (long)NV0 * 64;
  if (i < n_pb0) { pb0[i] = 0u; return; }
  i -= n_pb0;
  if (i < 32 * 32)   { We0[i] = f2bf(enc_w(w_enc0, 16, (int)i)); return; }
  i -= 32 * 32;
  if (i < 64 * 64)   { We1[i] = f2bf(enc_w(w_enc1, 32, (int)i)); return; }
  i -= 64 * 64;
  if (i < 128 * 128) { We2[i] = f2bf(enc_w(w_enc2, 64, (int)i)); return; }
  i -= 128 * 128;
  if (i < 128 * 192) { Wd0[i] = f2bf(dec_w(w_dec0, 192, 64, (int)i)); return; }
  i -= 128 * 192;
  if (i < 64 * 96)   { Wd1[i] = f2bf(dec_w(w_dec1, 96, 32, (int)i)); return; }
}

// ---------- pool decode: encoded u32 -> bf16 table ----------
__global__ __launch_bounds__(256) void pool_decode_k(const u32* __restrict__ buf,
                                                     u16* __restrict__ outbf, int n) {
  int i = blockIdx.x * 256 + threadIdx.x;
  if (i < n) outbf[i] = dec16((u16)(buf[i] >> 16));
}

// ---------- encoder GEMM, gather fused into A-operand, pooling fused into epilogue ----
// y[v] = leaky([f[v] | avg6(f[src[v]])] @ Wt^T + b);  outb = bf16(y);
// if POOL: atomicMax(pb[parent(v)*COUT+n], enc16(bf16(y))<<16), parent = v<np ? v : pmap[v]
template <int C, int COUT, bool POOL>
__global__ __launch_bounds__(256) void gemm_enc_k(
    const u16* __restrict__ fb, const int* __restrict__ src,
    const u16* __restrict__ Wt, const float* __restrict__ bias,
    u16* __restrict__ outb, u32* __restrict__ pb,
    const int* __restrict__ pmap, int nparent, int nv) {
  constexpr int K = 2 * C;
  constexpr int NT = COUT / 16;
  const int w = threadIdx.x >> 6, lane = threadIdx.x & 63;
  const int lr = lane & 15, lg = lane >> 4;
  const int vbase = blockIdx.x * 64 + w * 16;
  int arow = vbase + lr; if (arow >= nv) arow = nv - 1;

  int sidx[6];
#pragma unroll
  for (int kk = 0; kk < 6; ++kk) sidx[kk] = src[(size_t)arow * 6 + kk];

  f32x4 acc[NT] = {};
#pragma unroll
  for (int kt = 0; kt < K; kt += 32) {
    const int k = kt + lg * 8;
    bf16x8 a;
    if (k < C) {
      a = *(const bf16x8*)&fb[(size_t)arow * C + k];
    } else {
      const int c0 = k - C;
      float s[8] = {0.f, 0.f, 0.f, 0.f, 0.f, 0.f, 0.f, 0.f};
#pragma unroll
      for (int kk = 0; kk < 6; ++kk) {
        float nb[8];
        unpack8(*(const uint4*)&fb[(size_t)sidx[kk] * C + c0], nb);
#pragma unroll
        for (int j = 0; j < 8; ++j) s[j] += nb[j];
      }
#pragma unroll
      for (int j = 0; j < 8; ++j) s[j] *= (1.f / 6.f);
      uint4 p = pack8(s);
      a = *(bf16x8*)&p;
    }
#pragma unroll
    for (int nt = 0; nt < NT; ++nt) {
      bf16x8 b = *(const bf16x8*)&Wt[(size_t)(nt * 16 + lr) * K + k];
      acc[nt] = __builtin_amdgcn_mfma_f32_16x16x32_bf16(a, b, acc[nt], 0, 0, 0);
    }
  }

  int prow[4];
  if constexpr (POOL) {
#pragma unroll
    for (int r = 0; r < 4; ++r) {
      int v = vbase + lg * 4 + r;
      if (v < nv) prow[r] = (v < nparent) ? v : pmap[v];
    }
  }
#pragma unroll
  for (int nt = 0; nt < NT; ++nt) {
#pragma unroll
    for (int r = 0; r < 4; ++r) {
      int v = vbase + lg * 4 + r;
      if (v < nv) {
        int n = nt * 16 + lr;
        float y = acc[nt][r] + bias[n];
        y = (y >= 0.f) ? y : 0.3f * y;
        u16 hb = f2bf(y);
        outb[(size_t)v * COUT + n] = hb;
        if constexpr (POOL)
          atomicMax(&pb[(size_t)prow[r] * COUT + n], ((u32)enc16(hb)) << 16);
      }
    }
  }
}

// ---------- decoder GEMM (concat fused): [h|z] = [Ab[map[v]] | Bb[v]] @ Wt^T ----------
template <int CA, int CB, int COUT>
__global__ __launch_bounds__(256) void gemm_dec_k(
    const u16* __restrict__ Ab, const int* __restrict__ map,
    const u16* __restrict__ Bb, const u16* __restrict__ Wt,
    u16* __restrict__ h, float* __restrict__ z, int nv) {
  constexpr int K = CA + CB;
  constexpr int N = 2 * COUT;
  constexpr int NT = N / 16;
  const int w = threadIdx.x >> 6, lane = threadIdx.x & 63;
  const int lr = lane & 15, lg = lane >> 4;
  const int vbase = blockIdx.x * 64 + w * 16;
  int arow = vbase + lr; if (arow >= nv) arow = nv - 1;
  const int m = map[arow];

  f32x4 acc[NT] = {};
#pragma unroll
  for (int kt = 0; kt < K; kt += 32) {
    int k = kt + lg * 8;
    bf16x8 a = (k < CA) ? *(const bf16x8*)&Ab[(size_t)m * CA + k]
                        : *(const bf16x8*)&Bb[(size_t)arow * CB + (k - CA)];
#pragma unroll
    for (int nt = 0; nt < NT; ++nt) {
      bf16x8 b = *(const bf16x8*)&Wt[(size_t)(nt * 16 + lr) * K + k];
      acc[nt] = __builtin_amdgcn_mfma_f32_16x16x32_bf16(a, b, acc[nt], 0, 0, 0);
    }
  }
#pragma unroll
  for (int nt = 0; nt < NT; ++nt) {
#pragma unroll
    for (int r = 0; r < 4; ++r) {
      int v = vbase + lg * 4 + r;
      if (v < nv) {
        int n = nt * 16 + lr;
        float val = acc[nt][r];
        if (n < COUT) h[(size_t)v * COUT + n] = f2bf(val);
        else          z[(size_t)v * COUT + (n - COUT)] = val;
      }
    }
  }
}

// ---------- decoder combine: y = leaky(z + avg6(h) + b) ----------
template <int COUT, bool OUT32, bool OUTB>
__global__ __launch_bounds__(256) void combine_k(
    const u16* __restrict__ h, const float* __restrict__ z,
    const int* __restrict__ src, const float* __restrict__ bias,
    float* __restrict__ out32, u16* __restrict__ outb, int nv) {
  constexpr int TPV = COUT / 8;
  int gid = blockIdx.x * 256 + threadIdx.x;
  if (gid >= nv * TPV) return;
  int v = gid / TPV, c0 = (gid % TPV) * 8;
  const int* __restrict__ sp = src + (size_t)v * 6;
  float s[8] = {0.f, 0.f, 0.f, 0.f, 0.f, 0.f, 0.f, 0.f};
#pragma unroll
  for (int k = 0; k < 6; ++k) {
    float nb[8];
    unpack8(*(const uint4*)&h[(size_t)sp[k] * COUT + c0], nb);
#pragma unroll
    for (int j = 0; j < 8; ++j) s[j] += nb[j];
  }
  constexpr float inv6 = 1.f / 6.f;
  float4 z0 = *(const float4*)&z[(size_t)v * COUT + c0];
  float4 z1 = *(const float4*)&z[(size_t)v * COUT + c0 + 4];
  float4 b0 = *(const float4*)&bias[c0];
  float4 b1 = *(const float4*)&bias[c0 + 4];
  float y[8];
  y[0] = z0.x + s[0] * inv6 + b0.x; y[1] = z0.y + s[1] * inv6 + b0.y;
  y[2] = z0.z + s[2] * inv6 + b0.z; y[3] = z0.w + s[3] * inv6 + b0.w;
  y[4] = z1.x + s[4] * inv6 + b1.x; y[5] = z1.y + s[5] * inv6 + b1.y;
  y[6] = z1.z + s[6] * inv6 + b1.z; y[7] = z1.w + s[7] * inv6 + b1.w;
#pragma unroll
  for (int j = 0; j < 8; ++j) y[j] = (y[j] >= 0.f) ? y[j] : 0.3f * y[j];
  if constexpr (OUT32) {
    *(float4*)&out32[(size_t)v * COUT + c0]     = make_float4(y[0], y[1], y[2], y[3]);
    *(float4*)&out32[(size_t)v * COUT + c0 + 4] = make_float4(y[4], y[5], y[6], y[7]);
  }
  if constexpr (OUTB) *(uint4*)&outb[(size_t)v * COUT + c0] = pack8(y);
}

extern "C" void kernel_launch(void* const* d_in, const int* in_sizes, int n_in,
                              void* d_out, int out_size, void* d_ws, size_t ws_size,
                              hipStream_t stream) {
  const float* features = (const float*)d_in[0];
  const int* src2 = (const int*)d_in[1];
  const int* src1 = (const int*)d_in[3];
  const int* src0 = (const int*)d_in[5];
  const int* p21 = (const int*)d_in[7];
  const int* p10 = (const int*)d_in[8];
  const float* w_enc0 = (const float*)d_in[9];
  const float* b_enc0 = (const float*)d_in[10];
  const float* w_enc1 = (const float*)d_in[11];
  const float* b_enc1 = (const float*)d_in[12];
  const float* w_enc2 = (const float*)d_in[13];
  const float* b_enc2 = (const float*)d_in[14];
  const float* w_dec0 = (const float*)d_in[15];
  const float* b_dec0 = (const float*)d_in[16];
  const float* w_dec1 = (const float*)d_in[17];
  const float* b_dec1 = (const float*)d_in[18];

  // ---- linear workspace layout (~88 MB, no aliasing; all offsets 16B-aligned) ----
  u16* featb = (u16*)d_ws;                      // [NV2,16]
  u16* f2b   = featb + (size_t)NV2 * 16;        // [NV2,32]
  u16* f1pb  = f2b   + (size_t)NV2 * 32;        // [NV1,32]
  u16* f1b   = f1pb  + (size_t)NV1 * 32;        // [NV1,64]
  u16* f0pb  = f1b   + (size_t)NV1 * 64;        // [NV0,64]
  u16* f0b   = f0pb  + (size_t)NV0 * 64;        // [NV0,128]
  u16* h1b   = f0b   + (size_t)NV0 * 128;       // [NV1,64]
  u16* d1b   = h1b   + (size_t)NV1 * 64;        // [NV1,64]
  u16* h2b   = d1b   + (size_t)NV1 * 64;        // [NV2,32]
  u16* We0   = h2b   + (size_t)NV2 * 32;        // [32,32]
  u16* We1   = We0 + 32 * 32;                   // [64,64]
  u16* We2   = We1 + 64 * 64;                   // [128,128]
  u16* Wd0   = We2 + 128 * 128;                 // [128,192]
  u16* Wd1   = Wd0 + 128 * 192;                 // [64,96]
  float* z1  = (float*)(Wd1 + 64 * 96);         // [NV1,64]
  float* z2  = z1 + (size_t)NV1 * 64;           // [NV2,32]
  u32*  pb1  = (u32*)(z2 + (size_t)NV2 * 32);   // [NV1,32]
  u32*  pb0  = pb1 + (size_t)NV1 * 32;          // [NV0,64]
  float* out = (float*)d_out;                   // [NV2,32]

  auto cdiv = [](long long a, long long b) { return (int)((a + b - 1) / b); };

  // ---- 1: prep (cvt + zero pools + weight transforms) ----
  const long prep_n = (long)NV2 * 16 + (long)NV1 * 32 + (long)NV0 * 64 +
                      32 * 32 + 64 * 64 + 128 * 128 + 128 * 192 + 64 * 96;
  prep_all_k<<<cdiv(prep_n, 256), 256, 0, stream>>>(
      features, featb, pb1, pb0, w_enc0, We0, w_enc1, We1, w_enc2, We2,
      w_dec0, Wd0, w_dec1, Wd1);

  // ---- 2: encoder L2 (gather fused; pool 2->1 fused into epilogue) ----
  gemm_enc_k<16, 32, true><<<cdiv(NV2, 64), 256, 0, stream>>>(
      featb, src2, We0, b_enc0, f2b, pb1, p21, NV1, NV2);
  // ---- 3: decode pool 2->1 ----
  pool_decode_k<<<cdiv((size_t)NV1 * 32, 256), 256, 0, stream>>>(pb1, f1pb, NV1 * 32);
  // ---- 4: encoder L1 (pool 1->0 fused) ----
  gemm_enc_k<32, 64, true><<<cdiv(NV1, 64), 256, 0, stream>>>(
      f1pb, src1, We1, b_enc1, f1b, pb0, p10, NV0, NV1);
  // ---- 5: decode pool 1->0 ----
  pool_decode_k<<<cdiv((size_t)NV0 * 64, 256), 256, 0, stream>>>(pb0, f0pb, NV0 * 64);
  // ---- 6: encoder L0 ----
  gemm_enc_k<64, 128, false><<<cdiv(NV0, 64), 256, 0, stream>>>(
      f0pb, src0, We2, b_enc2, f0b, nullptr, nullptr, 0, NV0);
  // ---- 7: decoder L1 GEMM: [h1|z1] = [f0b[p10] | f1b] @ Wd0^T ----
  gemm_dec_k<128, 64, 64><<<cdiv(NV1, 64), 256, 0, stream>>>(
      f0b, p10, f1b, Wd0, h1b, z1, NV1);
  // ---- 8: decoder L1 combine -> d1b ----
  combine_k<64, false, true><<<cdiv((size_t)NV1 * 8, 256), 256, 0, stream>>>(
      h1b, z1, src1, b_dec0, nullptr, d1b, NV1);
  // ---- 9: decoder L2 GEMM: [h2|z2] = [d1b[p21] | f2b] @ Wd1^T ----
  gemm_dec_k<64, 32, 32><<<cdiv(NV2, 64), 256, 0, stream>>>(
      d1b, p21, f2b, Wd1, h2b, z2, NV2);
  // ---- 10: decoder L2 combine -> out ----
  combine_k<32, true, false><<<cdiv((size_t)NV2 * 4, 256), 256, 0, stream>>>(
      h2b, z2, src2, b_dec1, out, nullptr, NV2);
}

// Round 7
// 131.625 us; speedup vs baseline: 4.9586x; 1.0379x over previous
//
#include <hip/hip_runtime.h>

#define NV2 163842
#define NV1 40962
#define NV0 10242

using u32 = unsigned int;
using u16 = unsigned short;

typedef __attribute__((ext_vector_type(8))) short bf16x8;
typedef __attribute__((ext_vector_type(4))) float f32x4;

// RNE float->bf16 bits
__device__ __forceinline__ u16 f2bf(float f) {
  u32 u = __float_as_uint(f);
  return (u16)((u + 0x7FFFu + ((u >> 16) & 1u)) >> 16);
}
__device__ __forceinline__ void unpack8(uint4 u, float* f) {
  f[0] = __uint_as_float(u.x << 16); f[1] = __uint_as_float(u.x & 0xFFFF0000u);
  f[2] = __uint_as_float(u.y << 16); f[3] = __uint_as_float(u.y & 0xFFFF0000u);
  f[4] = __uint_as_float(u.z << 16); f[5] = __uint_as_float(u.z & 0xFFFF0000u);
  f[6] = __uint_as_float(u.w << 16); f[7] = __uint_as_float(u.w & 0xFFFF0000u);
}
__device__ __forceinline__ uint4 pack8(const float* f) {
  uint4 o;
  o.x = (u32)f2bf(f[0]) | ((u32)f2bf(f[1]) << 16);
  o.y = (u32)f2bf(f[2]) | ((u32)f2bf(f[3]) << 16);
  o.z = (u32)f2bf(f[4]) | ((u32)f2bf(f[5]) << 16);
  o.w = (u32)f2bf(f[6]) | ((u32)f2bf(f[7]) << 16);
  return o;
}
// orderable 16-bit encoding of bf16 bits (for atomicMax pooling in high half of u32)
__device__ __forceinline__ u16 enc16(u16 h) {
  return (h & 0x8000u) ? (u16)~h : (u16)(h | 0x8000u);
}
__device__ __forceinline__ u16 dec16(u16 e) {
  return (e & 0x8000u) ? (u16)(e & 0x7FFFu) : (u16)~e;
}

// ---------- weight transform values ----------
// Encoder GEMM A = [f | g]:  Wt[j][k] = (k<C) ? W[j][k]-W[j][C+k] : W[j][k]
__device__ __forceinline__ float enc_w(const float* __restrict__ W, int C, int i) {
  int j = i / (2 * C), k = i % (2 * C);
  float v = W[(size_t)j * 2 * C + k];
  if (k < C) v -= W[(size_t)j * 2 * C + C + k];
  return v;
}
// Decoder: rows j<COUT: Wn ; rows j>=COUT: Wl-Wn
__device__ __forceinline__ float dec_w(const float* __restrict__ W, int C, int COUT, int i) {
  int j = i / C, k = i % C;
  if (j < COUT) return W[(size_t)j * 2 * C + C + k];
  return W[(size_t)(j - COUT) * 2 * C + k] - W[(size_t)(j - COUT) * 2 * C + C + k];
}

// ---------- one-shot prep: cvt input to bf16, zero pool buffers, 5 weight preps ----------
__global__ __launch_bounds__(256) void prep_all_k(
    const float* __restrict__ features, u16* __restrict__ featb,
    u32* __restrict__ pb1, u32* __restrict__ pb0,
    const float* __restrict__ w_enc0, u16* __restrict__ We0,
    const float* __restrict__ w_enc1, u16* __restrict__ We1,
    const float* __restrict__ w_enc2, u16* __restrict__ We2,
    const float* __restrict__ w_dec0, u16* __restrict__ Wd0,
    const float* __restrict__ w_dec1, u16* __restrict__ Wd1) {
  long i = (long)blockIdx.x * 256 + threadIdx.x;
  const long n_cvt = (long)NV2 * 16;
  if (i < n_cvt) { featb[i] = f2bf(features[i]); return; }
  i -= n_cvt;
  const long n_pb1 = (long)NV1 * 32;
  if (i < n_pb1) { pb1[i] = 0u; return; }
  i -= n_pb1;
  const long n_pb0 = (long)NV0 * 64;
  if (i < n_pb0) { pb0[i] = 0u; return; }
  i -= n_pb0;
  if (i < 32 * 32)   { We0[i] = f2bf(enc_w(w_enc0, 16, (int)i)); return; }
  i -= 32 * 32;
  if (i < 64 * 64)   { We1[i] = f2bf(enc_w(w_enc1, 32, (int)i)); return; }
  i -= 64 * 64;
  if (i < 128 * 128) { We2[i] = f2bf(enc_w(w_enc2, 64, (int)i)); return; }
  i -= 128 * 128;
  if (i < 128 * 192) { Wd0[i] = f2bf(dec_w(w_dec0, 192, 64, (int)i)); return; }
  i -= 128 * 192;
  if (i < 64 * 96)   { Wd1[i] = f2bf(dec_w(w_dec1, 96, 32, (int)i)); return; }
}

// ---------- pool decode: parent value = max(tail-atomics value, parent's own row) ----
// own = the producing level's bf16 output; parent rows occupy the same linear indices.
__global__ __launch_bounds__(256) void pool_decode_k(const u32* __restrict__ buf,
                                                     const u16* __restrict__ own,
                                                     u16* __restrict__ outbf, int n) {
  int i = blockIdx.x * 256 + threadIdx.x;
  if (i < n) {
    u16 e = (u16)(buf[i] >> 16);
    u16 eo = enc16(own[i]);
    outbf[i] = dec16(e > eo ? e : eo);
  }
}

// ---------- encoder GEMM, gather fused into A-operand, tail pooling in epilogue ----
// y[v] = leaky([f[v] | avg6(f[src[v]])] @ Wt^T + b);  outb = bf16(y);
// if POOL && v>=nparent: atomicMax(pb[pmap[v]*COUT+n], enc16(bf16(y))<<16)
template <int C, int COUT, bool POOL>
__global__ __launch_bounds__(256) void gemm_enc_k(
    const u16* __restrict__ fb, const int* __restrict__ src,
    const u16* __restrict__ Wt, const float* __restrict__ bias,
    u16* __restrict__ outb, u32* __restrict__ pb,
    const int* __restrict__ pmap, int nparent, int nv) {
  constexpr int K = 2 * C;
  constexpr int NT = COUT / 16;
  const int w = threadIdx.x >> 6, lane = threadIdx.x & 63;
  const int lr = lane & 15, lg = lane >> 4;
  const int vbase = blockIdx.x * 64 + w * 16;
  int arow = vbase + lr; if (arow >= nv) arow = nv - 1;

  int sidx[6];
#pragma unroll
  for (int kk = 0; kk < 6; ++kk) sidx[kk] = src[(size_t)arow * 6 + kk];

  f32x4 acc[NT] = {};
#pragma unroll
  for (int kt = 0; kt < K; kt += 32) {
    const int k = kt + lg * 8;
    bf16x8 a;
    if (k < C) {
      a = *(const bf16x8*)&fb[(size_t)arow * C + k];
    } else {
      const int c0 = k - C;
      float s[8] = {0.f, 0.f, 0.f, 0.f, 0.f, 0.f, 0.f, 0.f};
#pragma unroll
      for (int kk = 0; kk < 6; ++kk) {
        float nb[8];
        unpack8(*(const uint4*)&fb[(size_t)sidx[kk] * C + c0], nb);
#pragma unroll
        for (int j = 0; j < 8; ++j) s[j] += nb[j];
      }
#pragma unroll
      for (int j = 0; j < 8; ++j) s[j] *= (1.f / 6.f);
      uint4 p = pack8(s);
      a = *(bf16x8*)&p;
    }
#pragma unroll
    for (int nt = 0; nt < NT; ++nt) {
      bf16x8 b = *(const bf16x8*)&Wt[(size_t)(nt * 16 + lr) * K + k];
      acc[nt] = __builtin_amdgcn_mfma_f32_16x16x32_bf16(a, b, acc[nt], 0, 0, 0);
    }
  }

  int prow[4];
  if constexpr (POOL) {
#pragma unroll
    for (int r = 0; r < 4; ++r) {
      int v = vbase + lg * 4 + r;
      prow[r] = (v < nv && v >= nparent) ? pmap[v] : -1;
    }
  }
#pragma unroll
  for (int nt = 0; nt < NT; ++nt) {
#pragma unroll
    for (int r = 0; r < 4; ++r) {
      int v = vbase + lg * 4 + r;
      if (v < nv) {
        int n = nt * 16 + lr;
        float y = acc[nt][r] + bias[n];
        y = (y >= 0.f) ? y : 0.3f * y;
        u16 hb = f2bf(y);
        outb[(size_t)v * COUT + n] = hb;
        if constexpr (POOL)
          if (prow[r] >= 0)
            atomicMax(&pb[(size_t)prow[r] * COUT + n], ((u32)enc16(hb)) << 16);
      }
    }
  }
}

// ---------- decoder GEMM (concat fused): [h|z] = [Ab[map[v]] | Bb[v]] @ Wt^T ----------
// h and z both stored bf16.
template <int CA, int CB, int COUT>
__global__ __launch_bounds__(256) void gemm_dec_k(
    const u16* __restrict__ Ab, const int* __restrict__ map,
    const u16* __restrict__ Bb, const u16* __restrict__ Wt,
    u16* __restrict__ h, u16* __restrict__ zb, int nv) {
  constexpr int K = CA + CB;
  constexpr int N = 2 * COUT;
  constexpr int NT = N / 16;
  const int w = threadIdx.x >> 6, lane = threadIdx.x & 63;
  const int lr = lane & 15, lg = lane >> 4;
  const int vbase = blockIdx.x * 64 + w * 16;
  int arow = vbase + lr; if (arow >= nv) arow = nv - 1;
  const int m = map[arow];

  f32x4 acc[NT] = {};
#pragma unroll
  for (int kt = 0; kt < K; kt += 32) {
    int k = kt + lg * 8;
    bf16x8 a = (k < CA) ? *(const bf16x8*)&Ab[(size_t)m * CA + k]
                        : *(const bf16x8*)&Bb[(size_t)arow * CB + (k - CA)];
#pragma unroll
    for (int nt = 0; nt < NT; ++nt) {
      bf16x8 b = *(const bf16x8*)&Wt[(size_t)(nt * 16 + lr) * K + k];
      acc[nt] = __builtin_amdgcn_mfma_f32_16x16x32_bf16(a, b, acc[nt], 0, 0, 0);
    }
  }
#pragma unroll
  for (int nt = 0; nt < NT; ++nt) {
#pragma unroll
    for (int r = 0; r < 4; ++r) {
      int v = vbase + lg * 4 + r;
      if (v < nv) {
        int n = nt * 16 + lr;
        u16 val = f2bf(acc[nt][r]);
        if (n < COUT) h[(size_t)v * COUT + n] = val;
        else          zb[(size_t)v * COUT + (n - COUT)] = val;
      }
    }
  }
}

// ---------- decoder combine: y = leaky(z + avg6(h) + b) ----------
template <int COUT, bool OUT32, bool OUTB>
__global__ __launch_bounds__(256) void combine_k(
    const u16* __restrict__ h, const u16* __restrict__ zb,
    const int* __restrict__ src, const float* __restrict__ bias,
    float* __restrict__ out32, u16* __restrict__ outb, int nv) {
  constexpr int TPV = COUT / 8;
  int gid = blockIdx.x * 256 + threadIdx.x;
  if (gid >= nv * TPV) return;
  int v = gid / TPV, c0 = (gid % TPV) * 8;
  const int* __restrict__ sp = src + (size_t)v * 6;
  float s[8] = {0.f, 0.f, 0.f, 0.f, 0.f, 0.f, 0.f, 0.f};
#pragma unroll
  for (int k = 0; k < 6; ++k) {
    float nb[8];
    unpack8(*(const uint4*)&h[(size_t)sp[k] * COUT + c0], nb);
#pragma unroll
    for (int j = 0; j < 8; ++j) s[j] += nb[j];
  }
  constexpr float inv6 = 1.f / 6.f;
  float zl[8];
  unpack8(*(const uint4*)&zb[(size_t)v * COUT + c0], zl);
  float4 b0 = *(const float4*)&bias[c0];
  float4 b1 = *(const float4*)&bias[c0 + 4];
  float y[8];
  y[0] = zl[0] + s[0] * inv6 + b0.x; y[1] = zl[1] + s[1] * inv6 + b0.y;
  y[2] = zl[2] + s[2] * inv6 + b0.z; y[3] = zl[3] + s[3] * inv6 + b0.w;
  y[4] = zl[4] + s[4] * inv6 + b1.x; y[5] = zl[5] + s[5] * inv6 + b1.y;
  y[6] = zl[6] + s[6] * inv6 + b1.z; y[7] = zl[7] + s[7] * inv6 + b1.w;
#pragma unroll
  for (int j = 0; j < 8; ++j) y[j] = (y[j] >= 0.f) ? y[j] : 0.3f * y[j];
  if constexpr (OUT32) {
    *(float4*)&out32[(size_t)v * COUT + c0]     = make_float4(y[0], y[1], y[2], y[3]);
    *(float4*)&out32[(size_t)v * COUT + c0 + 4] = make_float4(y[4], y[5], y[6], y[7]);
  }
  if constexpr (OUTB) *(uint4*)&outb[(size_t)v * COUT + c0] = pack8(y);
}

extern "C" void kernel_launch(void* const* d_in, const int* in_sizes, int n_in,
                              void* d_out, int out_size, void* d_ws, size_t ws_size,
                              hipStream_t stream) {
  const float* features = (const float*)d_in[0];
  const int* src2 = (const int*)d_in[1];
  const int* src1 = (const int*)d_in[3];
  const int* src0 = (const int*)d_in[5];
  const int* p21 = (const int*)d_in[7];
  const int* p10 = (const int*)d_in[8];
  const float* w_enc0 = (const float*)d_in[9];
  const float* b_enc0 = (const float*)d_in[10];
  const float* w_enc1 = (const float*)d_in[11];
  const float* b_enc1 = (const float*)d_in[12];
  const float* w_enc2 = (const float*)d_in[13];
  const float* b_enc2 = (const float*)d_in[14];
  const float* w_dec0 = (const float*)d_in[15];
  const float* b_dec0 = (const float*)d_in[16];
  const float* w_dec1 = (const float*)d_in[17];
  const float* b_dec1 = (const float*)d_in[18];

  // ---- linear workspace layout (~70 MB, no aliasing; all offsets 16B-aligned) ----
  u16* featb = (u16*)d_ws;                      // [NV2,16]
  u16* f2b   = featb + (size_t)NV2 * 16;        // [NV2,32]
  u16* f1pb  = f2b   + (size_t)NV2 * 32;        // [NV1,32]
  u16* f1b   = f1pb  + (size_t)NV1 * 32;        // [NV1,64]
  u16* f0pb  = f1b   + (size_t)NV1 * 64;        // [NV0,64]
  u16* f0b   = f0pb  + (size_t)NV0 * 64;        // [NV0,128]
  u16* h1b   = f0b   + (size_t)NV0 * 128;       // [NV1,64]
  u16* d1b   = h1b   + (size_t)NV1 * 64;        // [NV1,64]
  u16* h2b   = d1b   + (size_t)NV1 * 64;        // [NV2,32]
  u16* z1b   = h2b   + (size_t)NV2 * 32;        // [NV1,64]
  u16* z2b   = z1b   + (size_t)NV1 * 64;        // [NV2,32]
  u16* We0   = z2b   + (size_t)NV2 * 32;        // [32,32]
  u16* We1   = We0 + 32 * 32;                   // [64,64]
  u16* We2   = We1 + 64 * 64;                   // [128,128]
  u16* Wd0   = We2 + 128 * 128;                 // [128,192]
  u16* Wd1   = Wd0 + 128 * 192;                 // [64,96]
  u32* pb1   = (u32*)(Wd1 + 64 * 96);           // [NV1,32]
  u32* pb0   = pb1 + (size_t)NV1 * 32;          // [NV0,64]
  float* out = (float*)d_out;                   // [NV2,32]

  auto cdiv = [](long long a, long long b) { return (int)((a + b - 1) / b); };

  // ---- 1: prep (cvt + zero pools + weight transforms) ----
  const long prep_n = (long)NV2 * 16 + (long)NV1 * 32 + (long)NV0 * 64 +
                      32 * 32 + 64 * 64 + 128 * 128 + 128 * 192 + 64 * 96;
  prep_all_k<<<cdiv(prep_n, 256), 256, 0, stream>>>(
      features, featb, pb1, pb0, w_enc0, We0, w_enc1, We1, w_enc2, We2,
      w_dec0, Wd0, w_dec1, Wd1);

  // ---- 2: encoder L2 (gather fused; tail of pool 2->1 fused into epilogue) ----
  gemm_enc_k<16, 32, true><<<cdiv(NV2, 64), 256, 0, stream>>>(
      featb, src2, We0, b_enc0, f2b, pb1, p21, NV1, NV2);
  // ---- 3: decode pool 2->1 (max with identity-prefix rows of f2b) ----
  pool_decode_k<<<cdiv((size_t)NV1 * 32, 256), 256, 0, stream>>>(
      pb1, f2b, f1pb, NV1 * 32);
  // ---- 4: encoder L1 (pool 1->0 tail fused) ----
  gemm_enc_k<32, 64, true><<<cdiv(NV1, 64), 256, 0, stream>>>(
      f1pb, src1, We1, b_enc1, f1b, pb0, p10, NV0, NV1);
  // ---- 5: decode pool 1->0 ----
  pool_decode_k<<<cdiv((size_t)NV0 * 64, 256), 256, 0, stream>>>(
      pb0, f1b, f0pb, NV0 * 64);
  // ---- 6: encoder L0 ----
  gemm_enc_k<64, 128, false><<<cdiv(NV0, 64), 256, 0, stream>>>(
      f0pb, src0, We2, b_enc2, f0b, nullptr, nullptr, 0, NV0);
  // ---- 7: decoder L1 GEMM: [h1|z1] = [f0b[p10] | f1b] @ Wd0^T ----
  gemm_dec_k<128, 64, 64><<<cdiv(NV1, 64), 256, 0, stream>>>(
      f0b, p10, f1b, Wd0, h1b, z1b, NV1);
  // ---- 8: decoder L1 combine -> d1b ----
  combine_k<64, false, true><<<cdiv((size_t)NV1 * 8, 256), 256, 0, stream>>>(
      h1b, z1b, src1, b_dec0, nullptr, d1b, NV1);
  // ---- 9: decoder L2 GEMM: [h2|z2] = [d1b[p21] | f2b] @ Wd1^T ----
  gemm_dec_k<64, 32, 32><<<cdiv(NV2, 64), 256, 0, stream>>>(
      d1b, p21, f2b, Wd1, h2b, z2b, NV2);
  // ---- 10: decoder L2 combine -> out ----
  combine_k<32, true, false><<<cdiv((size_t)NV2 * 4, 256), 256, 0, stream>>>(
      h2b, z2b, src2, b_dec1, out, nullptr, NV2);
}